// Round 11
// baseline (256.894 us; speedup 1.0000x reference)
//
#include <hip/hip_runtime.h>
#include <math.h>

// Problem constants
constexpr int BATCH = 16384;
constexpr int IND   = 2048;   // INPUT
constexpr int HID   = 32;     // HIDDEN
constexpr int OUTD  = 512;    // OUTPUT

constexpr int AC = 512;       // actsum partial slices (k_act_c grid)

// FMA helpers on named float4s (no runtime-indexed arrays -> no scratch)
#define UPD4(C, A, S)                 \
  (C).x = fmaf((S), (A).x, (C).x);    \
  (C).y = fmaf((S), (A).y, (C).y);    \
  (C).z = fmaf((S), (A).z, (C).z);    \
  (C).w = fmaf((S), (A).w, (C).w);

#define DOT4(Z, A, W)                 \
  (Z) = fmaf((A).x, (W).x, (Z));      \
  (Z) = fmaf((A).y, (W).y, (Z));      \
  (Z) = fmaf((A).z, (W).z, (Z));      \
  (Z) = fmaf((A).w, (W).w, (Z));

// one 4-k micro-step of layer-1: 4 ds_read_b128 + 32 FMA
#define STEP4(XA, XB, KOFF)                                       \
  {                                                               \
    float4 w0v = *(const float4*)(&ws[((KOFF) + 0) * 36 + h0]);   \
    float4 w1v = *(const float4*)(&ws[((KOFF) + 1) * 36 + h0]);   \
    float4 w2v = *(const float4*)(&ws[((KOFF) + 2) * 36 + h0]);   \
    float4 w3v = *(const float4*)(&ws[((KOFF) + 3) * 36 + h0]);   \
    UPD4(acc0, w0v, (XA).x); UPD4(acc0, w1v, (XA).y);             \
    UPD4(acc0, w2v, (XA).z); UPD4(acc0, w3v, (XA).w);             \
    UPD4(acc1, w0v, (XB).x); UPD4(acc1, w1v, (XB).y);             \
    UPD4(acc1, w2v, (XB).z); UPD4(acc1, w3v, (XB).w);             \
  }

// ---------------------------------------------------------------------------
// K1: layer-1 GEMM. r7(10% occ) and r9(34% occ) both ran 79 us -> bottleneck
// is per-wave vmcnt(0) drain each 4-k step, NOT occupancy. Fix: explicit
// 16-k double-buffered x prefetch in registers (issue next group's 8 loads
// before computing current group). K-split x8: grid = 8 kq x 256 row-tiles
// = 2048 blocks. Thread = (2 rows, 4 h). w1T chunk [128][36] in LDS
// (conflict-free store mapping, r9-verified: 0 conflicts).
// ---------------------------------------------------------------------------
__global__ __launch_bounds__(256, 4) void k_act_q(
    const float* __restrict__ x, const float* __restrict__ w1,
    float* __restrict__ act_part) {
  const int tid = threadIdx.x;
  const int kq = blockIdx.x >> 8;          // 0..7 K-eighth
  const int bt = blockIdx.x & 255;         // row tile (64 rows)
  const int b0 = bt * 64;
  const int kbase = kq * 256;

  __shared__ float ws[128 * 36];           // [k][h], stride 36

  const int rg = tid >> 3;                 // 0..31 -> rows 2rg, 2rg+1
  const int h0 = (tid & 7) * 4;            // 0,4,...,28
  const int r0 = b0 + 2 * rg;

  float4 acc0{0, 0, 0, 0}, acc1{0, 0, 0, 0};

  for (int kc = 0; kc < 2; ++kc) {
    const int k0 = kbase + kc * 128;
    __syncthreads();
    // stage w1 chunk transposed; lanes h=tid&31 -> all 32 banks, 2-way free
    {
      const int h = tid & 31;
      const int kk0 = (tid >> 5) * 16;     // 0..112
#pragma unroll
      for (int u = 0; u < 4; ++u) {
        float4 wv = *(const float4*)(w1 + (size_t)h * IND + k0 + kk0 + 4 * u);
        ws[(kk0 + 4 * u + 0) * 36 + h] = wv.x;
        ws[(kk0 + 4 * u + 1) * 36 + h] = wv.y;
        ws[(kk0 + 4 * u + 2) * 36 + h] = wv.z;
        ws[(kk0 + 4 * u + 3) * 36 + h] = wv.w;
      }
    }
    __syncthreads();

    const float* xr0 = x + (size_t)r0 * IND + k0;
    const float* xr1 = xr0 + IND;

    // prefetch group 0 (16 k = 4 float4 per row)
    float4 ca0 = *(const float4*)(xr0 + 0),  ca1 = *(const float4*)(xr0 + 4);
    float4 ca2 = *(const float4*)(xr0 + 8),  ca3 = *(const float4*)(xr0 + 12);
    float4 cb0 = *(const float4*)(xr1 + 0),  cb1 = *(const float4*)(xr1 + 4);
    float4 cb2 = *(const float4*)(xr1 + 8),  cb3 = *(const float4*)(xr1 + 12);

#pragma unroll
    for (int g = 0; g < 8; ++g) {
      float4 na0, na1, na2, na3, nb0, nb1, nb2, nb3;
      if (g < 7) {                         // issue next group's loads EARLY
        const int kn = (g + 1) * 16;
        na0 = *(const float4*)(xr0 + kn + 0);  na1 = *(const float4*)(xr0 + kn + 4);
        na2 = *(const float4*)(xr0 + kn + 8);  na3 = *(const float4*)(xr0 + kn + 12);
        nb0 = *(const float4*)(xr1 + kn + 0);  nb1 = *(const float4*)(xr1 + kn + 4);
        nb2 = *(const float4*)(xr1 + kn + 8);  nb3 = *(const float4*)(xr1 + kn + 12);
      }
      const int kg = g * 16;
      STEP4(ca0, cb0, kg + 0);
      STEP4(ca1, cb1, kg + 4);
      STEP4(ca2, cb2, kg + 8);
      STEP4(ca3, cb3, kg + 12);
      if (g < 7) {
        ca0 = na0; ca1 = na1; ca2 = na2; ca3 = na3;
        cb0 = nb0; cb1 = nb1; cb2 = nb2; cb3 = nb3;
      }
    }
  }

  float* p = act_part + (size_t)kq * (BATCH * HID);
  *(float4*)(p + (size_t)r0 * HID + h0) = acc0;
  *(float4*)(p + (size_t)(r0 + 1) * HID + h0) = acc1;
}

// ---------------------------------------------------------------------------
// K1b: combine 8 K-eighth partials -> relu -> act; actsum block partials.
// grid = 512 x 256; thread owns one float4 of act.
// ---------------------------------------------------------------------------
__global__ __launch_bounds__(256) void k_act_c(
    const float* __restrict__ act_part, float* __restrict__ act,
    float* __restrict__ actsum_part) {
  const int tid = threadIdx.x;
  const int idx = blockIdx.x * 256 + tid;      // float4 index < 131072
  const float4* p = (const float4*)act_part;
  constexpr int STR = BATCH * HID / 4;

  float4 s{0.f, 0.f, 0.f, 0.f};
#pragma unroll
  for (int q = 0; q < 8; ++q) {
    float4 v = p[(size_t)q * STR + idx];
    s.x += v.x; s.y += v.y; s.z += v.z; s.w += v.w;
  }
  s.x = s.x > 0.f ? s.x : 0.f;  s.y = s.y > 0.f ? s.y : 0.f;
  s.z = s.z > 0.f ? s.z : 0.f;  s.w = s.w > 0.f ? s.w : 0.f;
  ((float4*)act)[idx] = s;

  __shared__ float asr[256 * 4];
  asr[tid * 4 + 0] = s.x; asr[tid * 4 + 1] = s.y;
  asr[tid * 4 + 2] = s.z; asr[tid * 4 + 3] = s.w;
  __syncthreads();
  if (tid < 32) {
    const int q = tid >> 2, j = tid & 3;       // h = q*4 + j
    float t = 0.f;
#pragma unroll
    for (int r = 0; r < 32; ++r) t += asr[(r * 8 + q) * 4 + j];
    actsum_part[blockIdx.x * HID + q * 4 + j] = t;
  }
}

// ---------------------------------------------------------------------------
// K2: privatized corr1 partials — NO atomics. Template BCH = batch rows per
// chunk. grid = 4 i-tiles x (BATCH/BCH) chunks. BCH=64 -> grid 1024
// (4 blk/CU, fixes r9's 1 blk/CU latency starvation); BCH=256 -> r9 layout.
// ---------------------------------------------------------------------------
template <int BCH>
__global__ __launch_bounds__(256, 2) void k_corr1p(
    const float* __restrict__ x, const float* __restrict__ act,
    float* __restrict__ corr1_part, float* __restrict__ xsum_part) {
  const int tid = threadIdx.x;
  const int i0 = (blockIdx.x & 3) * 512;
  const int chunk = blockIdx.x >> 2;
  const int b0 = chunk * BCH;

  __shared__ float act_s[BCH][HID];
  {
    const float4* ag = (const float4*)(act + (size_t)b0 * HID);
    float4* as = (float4*)(&act_s[0][0]);
#pragma unroll
    for (int q = 0; q < BCH / 32; ++q) as[tid + 256 * q] = ag[tid + 256 * q];
  }
  __syncthreads();

  const float2* __restrict__ xp = (const float2*)x;
  const int i2 = i0 / 2 + tid;

  float4 c00{0,0,0,0}, c01{0,0,0,0}, c02{0,0,0,0}, c03{0,0,0,0};
  float4 c04{0,0,0,0}, c05{0,0,0,0}, c06{0,0,0,0}, c07{0,0,0,0};
  float4 c10{0,0,0,0}, c11{0,0,0,0}, c12{0,0,0,0}, c13{0,0,0,0};
  float4 c14{0,0,0,0}, c15{0,0,0,0}, c16{0,0,0,0}, c17{0,0,0,0};
  float xs0 = 0.f, xs1 = 0.f;

#pragma unroll 2
  for (int b = 0; b < BCH; ++b) {
    float2 xv = xp[(size_t)(b0 + b) * (IND / 2) + i2];
    xs0 += xv.x; xs1 += xv.y;
    const float4* ar = (const float4*)(&act_s[b][0]);
    float4 a0 = ar[0], a1 = ar[1], a2 = ar[2], a3 = ar[3];
    float4 a4 = ar[4], a5 = ar[5], a6 = ar[6], a7 = ar[7];
    UPD4(c00, a0, xv.x); UPD4(c01, a1, xv.x); UPD4(c02, a2, xv.x); UPD4(c03, a3, xv.x);
    UPD4(c04, a4, xv.x); UPD4(c05, a5, xv.x); UPD4(c06, a6, xv.x); UPD4(c07, a7, xv.x);
    UPD4(c10, a0, xv.y); UPD4(c11, a1, xv.y); UPD4(c12, a2, xv.y); UPD4(c13, a3, xv.y);
    UPD4(c14, a4, xv.y); UPD4(c15, a5, xv.y); UPD4(c16, a6, xv.y); UPD4(c17, a7, xv.y);
  }

  const int ia = i0 + 2 * tid;
  float4* p0 = (float4*)(corr1_part + (size_t)chunk * (IND * HID) + (size_t)ia * HID);
  float4* p1 = (float4*)(corr1_part + (size_t)chunk * (IND * HID) + (size_t)(ia + 1) * HID);
  p0[0] = c00; p0[1] = c01; p0[2] = c02; p0[3] = c03;
  p0[4] = c04; p0[5] = c05; p0[6] = c06; p0[7] = c07;
  p1[0] = c10; p1[1] = c11; p1[2] = c12; p1[3] = c13;
  p1[4] = c14; p1[5] = c15; p1[6] = c16; p1[7] = c17;
  xsum_part[(size_t)chunk * IND + ia] = xs0;
  xsum_part[(size_t)chunk * IND + ia + 1] = xs1;
}

// ---------------------------------------------------------------------------
// K2b: deterministic reduce of corr1/xsum/actsum partials. Runtime nc1.
// ---------------------------------------------------------------------------
__global__ __launch_bounds__(256) void k_red1(
    const float* __restrict__ corr1_part, const float* __restrict__ xsum_part,
    const float* __restrict__ actsum_part,
    float* __restrict__ corr1, float* __restrict__ xsum,
    float* __restrict__ actsum, int nc1) {
  const int e = blockIdx.x * 256 + threadIdx.x;  // < 65536
  float s = 0.f;
#pragma unroll 8
  for (int c = 0; c < nc1; ++c) s += corr1_part[(size_t)c * (IND * HID) + e];
  corr1[e] = s;
  if (e < IND) {
    float t = 0.f;
#pragma unroll 8
    for (int c = 0; c < nc1; ++c) t += xsum_part[(size_t)c * IND + e];
    xsum[e] = t;
  }
  if (e < HID) {
    float t = 0.f;
#pragma unroll 8
    for (int c = 0; c < AC; ++c) t += actsum_part[(size_t)c * HID + e];
    actsum[e] = t;
  }
}

// ---------------------------------------------------------------------------
// K3: forward layer 2 + privatized corr2/outsum partials — NO atomics.
// Template BCH2 = batch rows per chunk. grid = 2 o-tiles x (BATCH/BCH2).
// BCH2=64 -> grid 512 (2 blk/CU); BCH2=128 -> r9 layout.
// ---------------------------------------------------------------------------
template <int BCH2>
__global__ __launch_bounds__(256, 2) void k_fwd2p(
    const float* __restrict__ act, const float* __restrict__ w2,
    float* __restrict__ out, float* __restrict__ corr2_part,
    float* __restrict__ outsum_part) {
  const int tid = threadIdx.x;
  const int o = (blockIdx.x & 1) * 256 + tid;
  const int chunk = blockIdx.x >> 1;
  const int b0 = chunk * BCH2;

  __shared__ float act_s[BCH2][HID];
  {
    const float4* ag = (const float4*)(act + (size_t)b0 * HID);
    float4* as = (float4*)(&act_s[0][0]);
#pragma unroll
    for (int q = 0; q < BCH2 / 32; ++q) as[tid + 256 * q] = ag[tid + 256 * q];
  }

  const float4* w2p = (const float4*)(w2 + (size_t)o * HID);
  float4 w0 = w2p[0], w1r = w2p[1], w2r_ = w2p[2], w3 = w2p[3];
  float4 w4 = w2p[4], w5 = w2p[5], w6 = w2p[6], w7 = w2p[7];

  float4 s0{0,0,0,0}, s1{0,0,0,0}, s2{0,0,0,0}, s3{0,0,0,0};
  float4 s4{0,0,0,0}, s5{0,0,0,0}, s6{0,0,0,0}, s7{0,0,0,0};
  float osum = 0.f;

  __syncthreads();
  for (int b = 0; b < BCH2; ++b) {
    const float4* ar = (const float4*)(&act_s[b][0]);
    float4 a0 = ar[0], a1 = ar[1], a2 = ar[2], a3 = ar[3];
    float4 a4 = ar[4], a5 = ar[5], a6 = ar[6], a7 = ar[7];
    float z = 0.f;
    DOT4(z, a0, w0); DOT4(z, a1, w1r); DOT4(z, a2, w2r_); DOT4(z, a3, w3);
    DOT4(z, a4, w4); DOT4(z, a5, w5);  DOT4(z, a6, w6);   DOT4(z, a7, w7);
    float ov = 1.0f / (1.0f + __expf(-z)) - 0.4f;
    out[(size_t)(b0 + b) * OUTD + o] = ov;
    osum += ov;
    UPD4(s0, a0, ov); UPD4(s1, a1, ov); UPD4(s2, a2, ov); UPD4(s3, a3, ov);
    UPD4(s4, a4, ov); UPD4(s5, a5, ov); UPD4(s6, a6, ov); UPD4(s7, a7, ov);
  }

  float* c = corr2_part + (size_t)chunk * (HID * OUTD) + o;
  c[0 * OUTD]  = s0.x; c[1 * OUTD]  = s0.y; c[2 * OUTD]  = s0.z; c[3 * OUTD]  = s0.w;
  c[4 * OUTD]  = s1.x; c[5 * OUTD]  = s1.y; c[6 * OUTD]  = s1.z; c[7 * OUTD]  = s1.w;
  c[8 * OUTD]  = s2.x; c[9 * OUTD]  = s2.y; c[10 * OUTD] = s2.z; c[11 * OUTD] = s2.w;
  c[12 * OUTD] = s3.x; c[13 * OUTD] = s3.y; c[14 * OUTD] = s3.z; c[15 * OUTD] = s3.w;
  c[16 * OUTD] = s4.x; c[17 * OUTD] = s4.y; c[18 * OUTD] = s4.z; c[19 * OUTD] = s4.w;
  c[20 * OUTD] = s5.x; c[21 * OUTD] = s5.y; c[22 * OUTD] = s5.z; c[23 * OUTD] = s5.w;
  c[24 * OUTD] = s6.x; c[25 * OUTD] = s6.y; c[26 * OUTD] = s6.z; c[27 * OUTD] = s6.w;
  c[28 * OUTD] = s7.x; c[29 * OUTD] = s7.y; c[30 * OUTD] = s7.z; c[31 * OUTD] = s7.w;
  outsum_part[(size_t)chunk * OUTD + o] = osum;
}

// ---------------------------------------------------------------------------
// K3b: deterministic reduce of corr2/outsum partials. Runtime nc2.
// ---------------------------------------------------------------------------
__global__ __launch_bounds__(256) void k_red2(
    const float* __restrict__ corr2_part, const float* __restrict__ outsum_part,
    float* __restrict__ corr2, float* __restrict__ outsum, int nc2) {
  const int e = blockIdx.x * 256 + threadIdx.x;  // < 16384
  float s = 0.f;
#pragma unroll 8
  for (int c = 0; c < nc2; ++c) s += corr2_part[(size_t)c * (HID * OUTD) + e];
  corr2[e] = s;
  if (e < OUTD) {
    float t = 0.f;
#pragma unroll 8
    for (int c = 0; c < nc2; ++c) t += outsum_part[(size_t)c * OUTD + e];
    outsum[e] = t;
  }
}

// ---------------------------------------------------------------------------
// K4: w1_new[h,i] = (w1[h,i] + dw1T[i,h]) / ||row h||_2
// ---------------------------------------------------------------------------
__global__ __launch_bounds__(256) void k_w1(
    const float* __restrict__ w1, const float* __restrict__ heb,
    const float* __restrict__ corr1, const float* __restrict__ xsum,
    const float* __restrict__ actsum, float* __restrict__ w1out) {
  const int h = blockIdx.x;
  const int tid = threadIdx.x;
  const float ash = actsum[h];
  const float4* heb4 = (const float4*)heb;

  float val[8];
  float ss = 0.f;
#pragma unroll
  for (int r = 0; r < 8; ++r) {
    const int i = tid + 256 * r;
    float4 c = heb4[(size_t)i * HID + h];
    float v = w1[(size_t)h * IND + i] + 16384.0f * c.w +
              c.x * corr1[(size_t)i * HID + h] + c.y * xsum[i] + c.z * ash;
    val[r] = v;
    ss += v * v;
  }

  __shared__ float red[256];
  red[tid] = ss;
  __syncthreads();
  for (int s = 128; s > 0; s >>= 1) {
    if (tid < s) red[tid] += red[tid + s];
    __syncthreads();
  }
  const float inv = 1.0f / sqrtf(red[0]);
#pragma unroll
  for (int r = 0; r < 8; ++r) {
    const int i = tid + 256 * r;
    w1out[(size_t)h * IND + i] = val[r] * inv;
  }
}

// ---------------------------------------------------------------------------
// K5: w2_new[o,h] = (w2[o,h] + dw2T[h,o]) / ||row o||_2
// ---------------------------------------------------------------------------
__global__ __launch_bounds__(256) void k_w2(
    const float* __restrict__ w2, const float* __restrict__ heb,
    const float* __restrict__ corr2, const float* __restrict__ actsum,
    const float* __restrict__ outsum, float* __restrict__ w2out) {
  const int o = blockIdx.x * 256 + threadIdx.x;
  const float oso = outsum[o];
  const float4* heb4 = (const float4*)heb;

  float val[HID];
  float ss = 0.f;
#pragma unroll
  for (int h = 0; h < HID; ++h) {
    float4 c = heb4[(size_t)(HID * IND) + (size_t)h * OUTD + o];
    float v = w2[(size_t)o * HID + h] + 16384.0f * c.w +
              c.x * corr2[(size_t)h * OUTD + o] + c.y * actsum[h] + c.z * oso;
    val[h] = v;
    ss += v * v;
  }
  const float inv = 1.0f / sqrtf(ss);
#pragma unroll
  for (int h = 0; h < HID; ++h) w2out[(size_t)o * HID + h] = val[h] * inv;
}

// ---------------------------------------------------------------------------
extern "C" void kernel_launch(void* const* d_in, const int* in_sizes, int n_in,
                              void* d_out, int out_size, void* d_ws,
                              size_t ws_size, hipStream_t stream) {
  const float* x   = (const float*)d_in[0];   // [16384, 2048]
  const float* w1  = (const float*)d_in[1];   // [32, 2048]
  const float* w2  = (const float*)d_in[2];   // [512, 32]
  const float* heb = (const float*)d_in[3];   // [81920, 4]

  float* out = (float*)d_out;                 // [16384, 512]
  float* w1o = out + (size_t)BATCH * OUTD;    // [32, 2048]
  float* w2o = w1o + (size_t)HID * IND;       // [512, 32]

  // Chunk counts: big layout (more blocks, better latency hiding) needs
  // ~89 MB of ws; fall back to the proven r9 layout (~29 MB) otherwise.
  const size_t bigFloats =
      (size_t)BATCH * HID + IND * HID + HID * OUTD + IND + HID + OUTD +
      (size_t)256 * IND * HID + (size_t)256 * IND +
      (size_t)256 * HID * OUTD + (size_t)256 * OUTD + (size_t)AC * HID;
  const bool big = ws_size >= bigFloats * sizeof(float);
  const int NC1 = big ? 256 : 64;    // corr1 b-chunks (BCH1 = BATCH/NC1)
  const int NC2 = big ? 256 : 128;   // corr2 b-chunks

  float* ws = (float*)d_ws;
  float* act         = ws;                                       // 524288
  float* corr1       = act + (size_t)BATCH * HID;                // 65536
  float* corr2       = corr1 + (size_t)IND * HID;                // 16384
  float* xsum        = corr2 + (size_t)HID * OUTD;               // 2048
  float* actsum      = xsum + IND;                               // 32
  float* outsum      = actsum + HID;                             // 512
  float* corr1_part  = outsum + OUTD;                            // NC1*65536
  float* xsum_part   = corr1_part + (size_t)NC1 * IND * HID;     // NC1*2048
  float* corr2_part  = xsum_part + (size_t)NC1 * IND;            // NC2*16384
  float* outsum_part = corr2_part + (size_t)NC2 * HID * OUTD;    // NC2*512
  float* actsum_part = outsum_part + (size_t)NC2 * OUTD;         // 512*32
  // act_part (8*524288 = 4,194,304 floats) aliases corr1_part
  // (NC1*65536 >= 4,194,304 for NC1 in {64,256}); consumed by k_act_c
  // before k_corr1p overwrites the region.
  float* act_part    = corr1_part;

  k_act_q<<<2048, 256, 0, stream>>>(x, w1, act_part);
  k_act_c<<<512, 256, 0, stream>>>(act_part, act, actsum_part);
  if (big) k_corr1p<64> <<<1024, 256, 0, stream>>>(x, act, corr1_part, xsum_part);
  else     k_corr1p<256><<<256,  256, 0, stream>>>(x, act, corr1_part, xsum_part);
  k_red1<<<256, 256, 0, stream>>>(corr1_part, xsum_part, actsum_part,
                                  corr1, xsum, actsum, NC1);
  if (big) k_fwd2p<64> <<<512, 256, 0, stream>>>(act, w2, out, corr2_part, outsum_part);
  else     k_fwd2p<128><<<256, 256, 0, stream>>>(act, w2, out, corr2_part, outsum_part);
  k_red2<<<64, 256, 0, stream>>>(corr2_part, outsum_part, corr2, outsum, NC2);
  k_w1<<<32, 256, 0, stream>>>(w1, heb, corr1, xsum, actsum, w1o);
  k_w2<<<2, 256, 0, stream>>>(w2, heb, corr2, actsum, outsum, w2o);
}

// Round 12
// 207.450 us; speedup vs baseline: 1.2383x; 1.2383x over previous
//
#include <hip/hip_runtime.h>
#include <math.h>

// Problem constants
constexpr int BATCH = 16384;
constexpr int IND   = 2048;   // INPUT
constexpr int HID   = 32;     // HIDDEN
constexpr int OUTD  = 512;    // OUTPUT

constexpr int NSL = 256;      // k_l1 blocks = corr1/xsum/actsum partial slices
constexpr int C2  = 128;      // corr2 b-chunks (r9-proven)

// FMA helpers on named float4s (no runtime-indexed arrays -> no scratch)
#define UPD4(C, A, S)                 \
  (C).x = fmaf((S), (A).x, (C).x);    \
  (C).y = fmaf((S), (A).y, (C).y);    \
  (C).z = fmaf((S), (A).z, (C).z);    \
  (C).w = fmaf((S), (A).w, (C).w);

#define DOT4(Z, A, W)                 \
  (Z) = fmaf((A).x, (W).x, (Z));      \
  (Z) = fmaf((A).y, (W).y, (Z));      \
  (Z) = fmaf((A).z, (W).z, (Z));      \
  (Z) = fmaf((A).w, (W).w, (Z));

// ---------------------------------------------------------------------------
// K1: FUSED layer-1. Phase A: act = relu(x @ w1T) with x tile [64][132] in
// LDS (coalesced staging) + w1T [128][36] (r9 conflict-free store mapping).
// Phase B: corr1T_part[blk][j][i] = sum_b x[b,i]*act[b,j] — re-stages the
// same 16 x tiles (L3-hot: x=134MB < 256MB L3) and does a register-tiled
// 4i x 4j GEMM per tile: per b, 2 ds_read_b128 for 16 FMA = VALU-bound.
// Transposed output => coalesced float4-over-i stores. xsum folded into
// phase B; actsum via in-block reduce. ZERO atomics.
// Rationale: r7/r9/r11 k_act all ~80-93us with VALUBusy ~= pure-FMA duty
// (17-20%) — the per-step 8-line x gather was L1-transaction-bound and
// occupancy-insensitive; fusing also halves x HBM traffic (268->134 MB).
// grid = 256 blocks x 256 threads; block owns rows [blk*64, +64).
// ---------------------------------------------------------------------------
__global__ __launch_bounds__(256, 2) void k_l1(
    const float* __restrict__ x, const float* __restrict__ w1,
    float* __restrict__ act, float* __restrict__ corr1T_part,
    float* __restrict__ xsum_part, float* __restrict__ actsum_part) {
  const int tid = threadIdx.x;
  const int blk = blockIdx.x;        // 0..255
  const int b0 = blk * 64;

  __shared__ float xs[64 * 132];     // x tile, row stride 132 (16B aligned)
  __shared__ float ws[128 * 36];     // w1T [k][h], stride 36
  __shared__ float as_[64 * 36];     // act tile [b][h], stride 36
  __shared__ float asr[256 * 4];     // actsum reduction scratch

  const int rg = tid >> 3;           // 0..31
  const int hg = tid & 7;            // 0..7
  const int h0 = hg * 4;
  const int r0 = 2 * rg;             // local rows r0, r0+1

  float4 acc0{0, 0, 0, 0}, acc1{0, 0, 0, 0};

  // ---------------- phase A: act ----------------
  for (int kc = 0; kc < 16; ++kc) {
    const int k0 = kc * 128;
    __syncthreads();                 // previous-iter LDS readers done
    // stage x tile: coalesced (lane -> consecutive float4, 2 rows/wave)
#pragma unroll
    for (int q = 0; q < 8; ++q) {
      const int m = tid + 256 * q;
      const int r = m >> 5, c4 = m & 31;
      float4 v = *(const float4*)(x + (size_t)(b0 + r) * IND + k0 + 4 * c4);
      *(float4*)(&xs[r * 132 + 4 * c4]) = v;
    }
    // stage w1T: lanes h=tid&31 -> banks (4k+h)%32 cover all 32, conflict-free
    {
      const int h = tid & 31;
      const int kk0 = (tid >> 5) * 16;
#pragma unroll
      for (int u = 0; u < 4; ++u) {
        float4 wv = *(const float4*)(w1 + (size_t)h * IND + k0 + kk0 + 4 * u);
        ws[(kk0 + 4 * u + 0) * 36 + h] = wv.x;
        ws[(kk0 + 4 * u + 1) * 36 + h] = wv.y;
        ws[(kk0 + 4 * u + 2) * 36 + h] = wv.z;
        ws[(kk0 + 4 * u + 3) * 36 + h] = wv.w;
      }
    }
    __syncthreads();

#pragma unroll 4
    for (int kk = 0; kk < 128; kk += 4) {
      float4 xa = *(const float4*)(&xs[r0 * 132 + kk]);
      float4 xb = *(const float4*)(&xs[(r0 + 1) * 132 + kk]);
      float4 w0v = *(const float4*)(&ws[(kk + 0) * 36 + h0]);
      float4 w1v = *(const float4*)(&ws[(kk + 1) * 36 + h0]);
      float4 w2v = *(const float4*)(&ws[(kk + 2) * 36 + h0]);
      float4 w3v = *(const float4*)(&ws[(kk + 3) * 36 + h0]);
      UPD4(acc0, w0v, xa.x); UPD4(acc0, w1v, xa.y);
      UPD4(acc0, w2v, xa.z); UPD4(acc0, w3v, xa.w);
      UPD4(acc1, w0v, xb.x); UPD4(acc1, w1v, xb.y);
      UPD4(acc1, w2v, xb.z); UPD4(acc1, w3v, xb.w);
    }
  }

  // relu
  acc0.x = acc0.x > 0.f ? acc0.x : 0.f;  acc0.y = acc0.y > 0.f ? acc0.y : 0.f;
  acc0.z = acc0.z > 0.f ? acc0.z : 0.f;  acc0.w = acc0.w > 0.f ? acc0.w : 0.f;
  acc1.x = acc1.x > 0.f ? acc1.x : 0.f;  acc1.y = acc1.y > 0.f ? acc1.y : 0.f;
  acc1.z = acc1.z > 0.f ? acc1.z : 0.f;  acc1.w = acc1.w > 0.f ? acc1.w : 0.f;

  // act -> global (coalesced) + LDS tile for phase B
  *(float4*)(act + (size_t)(b0 + r0) * HID + h0) = acc0;
  *(float4*)(act + (size_t)(b0 + r0 + 1) * HID + h0) = acc1;
  *(float4*)(&as_[r0 * 36 + h0]) = acc0;
  *(float4*)(&as_[(r0 + 1) * 36 + h0]) = acc1;

  // actsum partial
  asr[tid * 4 + 0] = acc0.x + acc1.x;
  asr[tid * 4 + 1] = acc0.y + acc1.y;
  asr[tid * 4 + 2] = acc0.z + acc1.z;
  asr[tid * 4 + 3] = acc0.w + acc1.w;
  __syncthreads();                   // as_ + asr complete for all threads
  if (tid < 32) {
    const int g = tid >> 2, j = tid & 3;  // h = g*4 + j
    float s = 0.f;
#pragma unroll
    for (int rr = 0; rr < 32; ++rr) s += asr[(rr * 8 + g) * 4 + j];
    actsum_part[blk * HID + g * 4 + j] = s;
  }

  // ---------------- phase B: corr1T + xsum ----------------
  const int il = tid & 31;           // i-group within tile
  const int jg = tid >> 5;           // 0..7
  const int i0 = il * 4;
  const int j0 = jg * 4;

  for (int t = 0; t < 16; ++t) {
    const int k0 = t * 128;
    __syncthreads();                 // xs free to overwrite
#pragma unroll
    for (int q = 0; q < 8; ++q) {    // restage x tile (L3-hot)
      const int m = tid + 256 * q;
      const int r = m >> 5, c4 = m & 31;
      float4 v = *(const float4*)(x + (size_t)(b0 + r) * IND + k0 + 4 * c4);
      *(float4*)(&xs[r * 132 + 4 * c4]) = v;
    }
    __syncthreads();

    float4 cj0{0,0,0,0}, cj1{0,0,0,0}, cj2{0,0,0,0}, cj3{0,0,0,0};
    float4 xs4{0,0,0,0};
#pragma unroll 4
    for (int b = 0; b < 64; ++b) {
      float4 xv = *(const float4*)(&xs[b * 132 + i0]);
      float4 av = *(const float4*)(&as_[b * 36 + j0]);   // 2-addr broadcast
      UPD4(cj0, xv, av.x); UPD4(cj1, xv, av.y);
      UPD4(cj2, xv, av.z); UPD4(cj3, xv, av.w);
      xs4.x += xv.x; xs4.y += xv.y; xs4.z += xv.z; xs4.w += xv.w;
    }

    const int ig = k0 + i0;          // global i
    float* base = corr1T_part + (size_t)blk * (IND * HID);
    *(float4*)(base + (size_t)(j0 + 0) * IND + ig) = cj0;  // coalesced over i
    *(float4*)(base + (size_t)(j0 + 1) * IND + ig) = cj1;
    *(float4*)(base + (size_t)(j0 + 2) * IND + ig) = cj2;
    *(float4*)(base + (size_t)(j0 + 3) * IND + ig) = cj3;
    if (jg == 0)
      *(float4*)(xsum_part + (size_t)blk * IND + ig) = xs4;
  }
}

// ---------------------------------------------------------------------------
// K1b: deterministic reduce of corr1T/xsum/actsum partials (256 slices).
// grid = 256 x 256; scalar lanes, coalesced per slice.
// ---------------------------------------------------------------------------
__global__ __launch_bounds__(256) void k_red1(
    const float* __restrict__ c1p, const float* __restrict__ xsp,
    const float* __restrict__ asp,
    float* __restrict__ corr1T, float* __restrict__ xsum,
    float* __restrict__ actsum) {
  const int e = blockIdx.x * 256 + threadIdx.x;  // < 65536
  float s = 0.f;
#pragma unroll 8
  for (int c = 0; c < NSL; ++c) s += c1p[(size_t)c * (IND * HID) + e];
  corr1T[e] = s;
  if (e < IND) {
    float t = 0.f;
#pragma unroll 8
    for (int c = 0; c < NSL; ++c) t += xsp[(size_t)c * IND + e];
    xsum[e] = t;
  }
  if (e < HID) {
    float t = 0.f;
#pragma unroll 8
    for (int c = 0; c < NSL; ++c) t += asp[(size_t)c * HID + e];
    actsum[e] = t;
  }
}

// ---------------------------------------------------------------------------
// K3: forward layer 2 + privatized corr2/outsum partials — r9-proven config.
// grid = 2 o-tiles x 128 b-chunks(128 b) = 256 blocks; thread owns one o.
// ---------------------------------------------------------------------------
__global__ __launch_bounds__(256, 2) void k_fwd2p(
    const float* __restrict__ act, const float* __restrict__ w2,
    float* __restrict__ out, float* __restrict__ corr2_part,
    float* __restrict__ outsum_part) {
  const int tid = threadIdx.x;
  const int o = (blockIdx.x & 1) * 256 + tid;
  const int chunk = blockIdx.x >> 1;
  const int b0 = chunk * 128;

  __shared__ float act_s[128][HID];
  {
    const float4* ag = (const float4*)(act + (size_t)b0 * HID);
    float4* as = (float4*)(&act_s[0][0]);
#pragma unroll
    for (int q = 0; q < 4; ++q) as[tid + 256 * q] = ag[tid + 256 * q];
  }

  const float4* w2p = (const float4*)(w2 + (size_t)o * HID);
  float4 w0 = w2p[0], w1r = w2p[1], w2r_ = w2p[2], w3 = w2p[3];
  float4 w4 = w2p[4], w5 = w2p[5], w6 = w2p[6], w7 = w2p[7];

  float4 s0{0,0,0,0}, s1{0,0,0,0}, s2{0,0,0,0}, s3{0,0,0,0};
  float4 s4{0,0,0,0}, s5{0,0,0,0}, s6{0,0,0,0}, s7{0,0,0,0};
  float osum = 0.f;

  __syncthreads();
  for (int b = 0; b < 128; ++b) {
    const float4* ar = (const float4*)(&act_s[b][0]);
    float4 a0 = ar[0], a1 = ar[1], a2 = ar[2], a3 = ar[3];
    float4 a4 = ar[4], a5 = ar[5], a6 = ar[6], a7 = ar[7];
    float z = 0.f;
    DOT4(z, a0, w0); DOT4(z, a1, w1r); DOT4(z, a2, w2r_); DOT4(z, a3, w3);
    DOT4(z, a4, w4); DOT4(z, a5, w5);  DOT4(z, a6, w6);   DOT4(z, a7, w7);
    float ov = 1.0f / (1.0f + __expf(-z)) - 0.4f;
    out[(size_t)(b0 + b) * OUTD + o] = ov;
    osum += ov;
    UPD4(s0, a0, ov); UPD4(s1, a1, ov); UPD4(s2, a2, ov); UPD4(s3, a3, ov);
    UPD4(s4, a4, ov); UPD4(s5, a5, ov); UPD4(s6, a6, ov); UPD4(s7, a7, ov);
  }

  float* c = corr2_part + (size_t)chunk * (HID * OUTD) + o;
  c[0 * OUTD]  = s0.x; c[1 * OUTD]  = s0.y; c[2 * OUTD]  = s0.z; c[3 * OUTD]  = s0.w;
  c[4 * OUTD]  = s1.x; c[5 * OUTD]  = s1.y; c[6 * OUTD]  = s1.z; c[7 * OUTD]  = s1.w;
  c[8 * OUTD]  = s2.x; c[9 * OUTD]  = s2.y; c[10 * OUTD] = s2.z; c[11 * OUTD] = s2.w;
  c[12 * OUTD] = s3.x; c[13 * OUTD] = s3.y; c[14 * OUTD] = s3.z; c[15 * OUTD] = s3.w;
  c[16 * OUTD] = s4.x; c[17 * OUTD] = s4.y; c[18 * OUTD] = s4.z; c[19 * OUTD] = s4.w;
  c[20 * OUTD] = s5.x; c[21 * OUTD] = s5.y; c[22 * OUTD] = s5.z; c[23 * OUTD] = s5.w;
  c[24 * OUTD] = s6.x; c[25 * OUTD] = s6.y; c[26 * OUTD] = s6.z; c[27 * OUTD] = s6.w;
  c[28 * OUTD] = s7.x; c[29 * OUTD] = s7.y; c[30 * OUTD] = s7.z; c[31 * OUTD] = s7.w;
  outsum_part[(size_t)chunk * OUTD + o] = osum;
}

// ---------------------------------------------------------------------------
// K3b: deterministic reduce of corr2/outsum partials (128 slices).
// ---------------------------------------------------------------------------
__global__ __launch_bounds__(256) void k_red2(
    const float* __restrict__ corr2_part, const float* __restrict__ outsum_part,
    float* __restrict__ corr2, float* __restrict__ outsum) {
  const int e = blockIdx.x * 256 + threadIdx.x;  // < 16384
  float s = 0.f;
#pragma unroll 8
  for (int c = 0; c < C2; ++c) s += corr2_part[(size_t)c * (HID * OUTD) + e];
  corr2[e] = s;
  if (e < OUTD) {
    float t = 0.f;
#pragma unroll 8
    for (int c = 0; c < C2; ++c) t += outsum_part[(size_t)c * OUTD + e];
    outsum[e] = t;
  }
}

// ---------------------------------------------------------------------------
// K4: w1_new[h,i] = (w1[h,i] + dw1T[i,h]) / ||row h||_2
// corr1 now TRANSPOSED: corr1T[h][i] -> coalesced reads.
// dw1T[i,h] = B*c1[i,h,3] + c1[i,h,0]*corr1T[h,i] + c1[i,h,1]*xsum[i]
//           + c1[i,h,2]*actsum[h];  c1 row index = i*32+h (unchanged).
// ---------------------------------------------------------------------------
__global__ __launch_bounds__(256) void k_w1(
    const float* __restrict__ w1, const float* __restrict__ heb,
    const float* __restrict__ corr1T, const float* __restrict__ xsum,
    const float* __restrict__ actsum, float* __restrict__ w1out) {
  const int h = blockIdx.x;
  const int tid = threadIdx.x;
  const float ash = actsum[h];
  const float4* heb4 = (const float4*)heb;

  float val[8];
  float ss = 0.f;
#pragma unroll
  for (int r = 0; r < 8; ++r) {
    const int i = tid + 256 * r;
    float4 c = heb4[(size_t)i * HID + h];
    float v = w1[(size_t)h * IND + i] + 16384.0f * c.w +
              c.x * corr1T[(size_t)h * IND + i] + c.y * xsum[i] + c.z * ash;
    val[r] = v;
    ss += v * v;
  }

  __shared__ float red[256];
  red[tid] = ss;
  __syncthreads();
  for (int s = 128; s > 0; s >>= 1) {
    if (tid < s) red[tid] += red[tid + s];
    __syncthreads();
  }
  const float inv = 1.0f / sqrtf(red[0]);
#pragma unroll
  for (int r = 0; r < 8; ++r) {
    const int i = tid + 256 * r;
    w1out[(size_t)h * IND + i] = val[r] * inv;
  }
}

// ---------------------------------------------------------------------------
// K5: w2_new[o,h] = (w2[o,h] + dw2T[h,o]) / ||row o||_2
// ---------------------------------------------------------------------------
__global__ __launch_bounds__(256) void k_w2(
    const float* __restrict__ w2, const float* __restrict__ heb,
    const float* __restrict__ corr2, const float* __restrict__ actsum,
    const float* __restrict__ outsum, float* __restrict__ w2out) {
  const int o = blockIdx.x * 256 + threadIdx.x;
  const float oso = outsum[o];
  const float4* heb4 = (const float4*)heb;

  float val[HID];
  float ss = 0.f;
#pragma unroll
  for (int h = 0; h < HID; ++h) {
    float4 c = heb4[(size_t)(HID * IND) + (size_t)h * OUTD + o];
    float v = w2[(size_t)o * HID + h] + 16384.0f * c.w +
              c.x * corr2[(size_t)h * OUTD + o] + c.y * actsum[h] + c.z * oso;
    val[h] = v;
    ss += v * v;
  }
  const float inv = 1.0f / sqrtf(ss);
#pragma unroll
  for (int h = 0; h < HID; ++h) w2out[(size_t)o * HID + h] = val[h] * inv;
}

// ---------------------------------------------------------------------------
extern "C" void kernel_launch(void* const* d_in, const int* in_sizes, int n_in,
                              void* d_out, int out_size, void* d_ws,
                              size_t ws_size, hipStream_t stream) {
  const float* x   = (const float*)d_in[0];   // [16384, 2048]
  const float* w1  = (const float*)d_in[1];   // [32, 2048]
  const float* w2  = (const float*)d_in[2];   // [512, 32]
  const float* heb = (const float*)d_in[3];   // [81920, 4]

  float* out = (float*)d_out;                 // [16384, 512]
  float* w1o = out + (size_t)BATCH * OUTD;    // [32, 2048]
  float* w2o = w1o + (size_t)HID * IND;       // [512, 32]

  // ws_size ~537 MB (observed via the harness poison fill) — layout ~80 MB.
  float* ws = (float*)d_ws;
  float* act         = ws;                                       // 524288
  float* corr1T      = act + (size_t)BATCH * HID;                // 65536 [h][i]
  float* corr2       = corr1T + (size_t)IND * HID;               // 16384
  float* xsum        = corr2 + (size_t)HID * OUTD;               // 2048
  float* actsum      = xsum + IND;                               // 32
  float* outsum      = actsum + HID;                             // 512
  float* corr1T_part = outsum + OUTD;                            // 256*65536
  float* xsum_part   = corr1T_part + (size_t)NSL * IND * HID;    // 256*2048
  float* actsum_part = xsum_part + (size_t)NSL * IND;            // 256*32
  float* corr2_part  = actsum_part + (size_t)NSL * HID;          // 128*16384
  float* outsum_part = corr2_part + (size_t)C2 * HID * OUTD;     // 128*512

  k_l1   <<<256, 256, 0, stream>>>(x, w1, act, corr1T_part, xsum_part,
                                   actsum_part);
  k_red1 <<<256, 256, 0, stream>>>(corr1T_part, xsum_part, actsum_part,
                                   corr1T, xsum, actsum);
  k_fwd2p<<<256, 256, 0, stream>>>(act, w2, out, corr2_part, outsum_part);
  k_red2 <<<64, 256, 0, stream>>>(corr2_part, outsum_part, corr2, outsum);
  k_w1   <<<32, 256, 0, stream>>>(w1, heb, corr1T, xsum, actsum, w1o);
  k_w2   <<<2, 256, 0, stream>>>(w2, heb, corr2, actsum, outsum, w2o);
}

// Round 13
// 167.597 us; speedup vs baseline: 1.5328x; 1.2378x over previous
//
#include <hip/hip_runtime.h>
#include <math.h>

// Problem constants
constexpr int BATCH = 16384;
constexpr int IND   = 2048;   // INPUT
constexpr int HID   = 32;     // HIDDEN
constexpr int OUTD  = 512;    // OUTPUT

constexpr int NSL = 256;      // k_l1 blocks = corr1/xsum/actsum partial slices
constexpr int C2  = 128;      // corr2 b-chunks (r9-proven)

constexpr int SA = 136;       // bf16 row stride, phase-A tiles (128 k + pad)
constexpr int SB = 72;        // bf16 row stride, phase-B tiles (64 b + pad)

typedef __attribute__((ext_vector_type(8))) short bf16x8;
typedef __attribute__((ext_vector_type(4))) float f32x4;

__device__ __forceinline__ unsigned short f2bf(float f) {
  unsigned u = __float_as_uint(f);
  u += 0x7FFFu + ((u >> 16) & 1u);          // round-to-nearest-even
  return (unsigned short)(u >> 16);
}
__device__ __forceinline__ float bf2f(unsigned short h) {
  return __uint_as_float(((unsigned)h) << 16);
}
__device__ __forceinline__ void split2(float f, unsigned short& hi,
                                       unsigned short& lo) {
  hi = f2bf(f);
  lo = f2bf(f - bf2f(hi));
}

// FMA helpers (still used by k_fwd2p)
#define UPD4(C, A, S)                 \
  (C).x = fmaf((S), (A).x, (C).x);    \
  (C).y = fmaf((S), (A).y, (C).y);    \
  (C).z = fmaf((S), (A).z, (C).z);    \
  (C).w = fmaf((S), (A).w, (C).w);

#define DOT4(Z, A, W)                 \
  (Z) = fmaf((A).x, (W).x, (Z));      \
  (Z) = fmaf((A).y, (W).y, (Z));      \
  (Z) = fmaf((A).z, (W).z, (Z));      \
  (Z) = fmaf((A).w, (W).w, (Z));

// ---------------------------------------------------------------------------
// K1: FUSED layer-1, MFMA version. r12 fp32 version was LDS-instr bound
// (VALUBusy 27% = pure FMA duty; ~20K ds_read_b128/CU x 12cyc ~= 102us).
// Phase A: act = relu(x @ w1T) via mfma_f32_16x16x32_bf16 with SPLIT bf16
// (x=xh+xl, w=wh+wl; 3 products; error ~1e-4 in z — out needs precision).
// Phase B: corr1T = x^T @ act + xsum via PLAIN bf16 MFMA (normalization of
// w1_new makes 0.4% corr error ~2e-5 on output). x^T staged bf16-transposed
// [i][b]; act^T [h][b] written from phase-A C-fragments; xsum = extra MFMA
// against a ones-column tile. Frag maps: A/B lane l -> 8 contig k at
// (l>>4)*8, row/col = l&15; C/D col=l&15, row=(l>>4)*4+reg (m89-verified).
// grid = 256 x 256 (4 waves); wave w owns b-rows 16w..16w+15 (phase A) and
// i-tiles {2w, 2w+1} x j-tiles {0,1,ones} (phase B).
// ---------------------------------------------------------------------------
__global__ __launch_bounds__(256) void k_l1(
    const float* __restrict__ x, const float* __restrict__ w1,
    float* __restrict__ act, float* __restrict__ corr1T_part,
    float* __restrict__ xsum_part, float* __restrict__ actsum_part) {
  const int tid = threadIdx.x;
  const int blk = blockIdx.x;
  const int b0 = blk * 64;
  const int lane = tid & 63;
  const int wv = tid >> 6;                 // 0..3
  const int arow = lane & 15;              // frag row/col index
  const int ksub = (lane >> 4) * 8;        // frag k-offset

  __shared__ unsigned short xh_s[64 * SA];
  __shared__ unsigned short xl_s[64 * SA];
  __shared__ unsigned short wh_s[32 * SA];
  __shared__ unsigned short wl_s[32 * SA];
  __shared__ unsigned short xsT[128 * SB];   // phase B: x^T bf16 [i][b]
  __shared__ unsigned short asT[48 * SB];    // act^T bf16 [h][b]; rows 32..47 = ones/zeros
  __shared__ float asum_s[32][16];

  // init ones-column tile rows 32..47 (row 32 = 1.0 for b<64, rest 0)
  for (int e = tid; e < 16 * SB; e += 256)
    asT[32 * SB + e] = (e < 64) ? (unsigned short)0x3F80 : (unsigned short)0;

  // ---------------- phase A: act = relu(x @ w1T), split bf16 ----------------
  f32x4 accA0 = {0.f, 0.f, 0.f, 0.f};   // h 0..15
  f32x4 accA1 = {0.f, 0.f, 0.f, 0.f};   // h 16..31

  const int rp = tid >> 3;               // 0..31 -> rows 2rp, 2rp+1
  const int kg = (tid & 7) * 16;         // k-group within chunk
  const int wh_r = tid >> 3;             // w-stage row 0..31
  for (int kc = 0; kc < 16; ++kc) {
    const int k0 = kc * 128;
    __syncthreads();
    {  // stage x (hi/lo) — coalesced reads, 4-contig bf16 writes
      const float* xr0 = x + (size_t)(b0 + 2 * rp) * IND + k0 + kg;
      const float* xr1 = xr0 + IND;
#pragma unroll
      for (int d4 = 0; d4 < 4; ++d4) {
        float4 v0 = *(const float4*)(xr0 + 4 * d4);
        float4 v1 = *(const float4*)(xr1 + 4 * d4);
        ushort4 h0, l0, h1, l1;
        split2(v0.x, h0.x, l0.x); split2(v0.y, h0.y, l0.y);
        split2(v0.z, h0.z, l0.z); split2(v0.w, h0.w, l0.w);
        split2(v1.x, h1.x, l1.x); split2(v1.y, h1.y, l1.y);
        split2(v1.z, h1.z, l1.z); split2(v1.w, h1.w, l1.w);
        const int cb = kg + 4 * d4;
        *(ushort4*)(&xh_s[(2 * rp) * SA + cb]) = h0;
        *(ushort4*)(&xh_s[(2 * rp + 1) * SA + cb]) = h1;
        *(ushort4*)(&xl_s[(2 * rp) * SA + cb]) = l0;
        *(ushort4*)(&xl_s[(2 * rp + 1) * SA + cb]) = l1;
      }
    }
    {  // stage w1 (hi/lo) — natural [h][k] layout, no transpose
      const float* wr = w1 + (size_t)wh_r * IND + k0 + kg;
#pragma unroll
      for (int d4 = 0; d4 < 4; ++d4) {
        float4 v = *(const float4*)(wr + 4 * d4);
        ushort4 h, l;
        split2(v.x, h.x, l.x); split2(v.y, h.y, l.y);
        split2(v.z, h.z, l.z); split2(v.w, h.w, l.w);
        const int cb = kg + 4 * d4;
        *(ushort4*)(&wh_s[wh_r * SA + cb]) = h;
        *(ushort4*)(&wl_s[wh_r * SA + cb]) = l;
      }
    }
    __syncthreads();

#pragma unroll
    for (int ks = 0; ks < 4; ++ks) {
      const int kk = ks * 32 + ksub;
      bf16x8 ah = *(const bf16x8*)(&xh_s[(wv * 16 + arow) * SA + kk]);
      bf16x8 al = *(const bf16x8*)(&xl_s[(wv * 16 + arow) * SA + kk]);
      bf16x8 bh0 = *(const bf16x8*)(&wh_s[arow * SA + kk]);
      bf16x8 bl0 = *(const bf16x8*)(&wl_s[arow * SA + kk]);
      bf16x8 bh1 = *(const bf16x8*)(&wh_s[(16 + arow) * SA + kk]);
      bf16x8 bl1 = *(const bf16x8*)(&wl_s[(16 + arow) * SA + kk]);
      accA0 = __builtin_amdgcn_mfma_f32_16x16x32_bf16(ah, bh0, accA0, 0, 0, 0);
      accA0 = __builtin_amdgcn_mfma_f32_16x16x32_bf16(ah, bl0, accA0, 0, 0, 0);
      accA0 = __builtin_amdgcn_mfma_f32_16x16x32_bf16(al, bh0, accA0, 0, 0, 0);
      accA1 = __builtin_amdgcn_mfma_f32_16x16x32_bf16(ah, bh1, accA1, 0, 0, 0);
      accA1 = __builtin_amdgcn_mfma_f32_16x16x32_bf16(ah, bl1, accA1, 0, 0, 0);
      accA1 = __builtin_amdgcn_mfma_f32_16x16x32_bf16(al, bh1, accA1, 0, 0, 0);
    }
  }

  // relu
#pragma unroll
  for (int r = 0; r < 4; ++r) {
    accA0[r] = fmaxf(accA0[r], 0.f);
    accA1[r] = fmaxf(accA1[r], 0.f);
  }

  // C layout: col = lane&15 (h), row = (lane>>4)*4 + r (b within wave tile)
  const int bl = wv * 16 + ((lane >> 4) << 2);  // local b of reg 0
  const int hcol = arow;
#pragma unroll
  for (int r = 0; r < 4; ++r) {
    act[(size_t)(b0 + bl + r) * HID + hcol] = accA0[r];
    act[(size_t)(b0 + bl + r) * HID + 16 + hcol] = accA1[r];
  }
  {  // act^T bf16 tile for phase B (4 contig b per lane)
    ushort4 pa, pb;
    pa.x = f2bf(accA0[0]); pa.y = f2bf(accA0[1]);
    pa.z = f2bf(accA0[2]); pa.w = f2bf(accA0[3]);
    pb.x = f2bf(accA1[0]); pb.y = f2bf(accA1[1]);
    pb.z = f2bf(accA1[2]); pb.w = f2bf(accA1[3]);
    *(ushort4*)(&asT[hcol * SB + bl]) = pa;
    *(ushort4*)(&asT[(16 + hcol) * SB + bl]) = pb;
  }
  asum_s[hcol][wv * 4 + (lane >> 4)] =
      accA0[0] + accA0[1] + accA0[2] + accA0[3];
  asum_s[16 + hcol][wv * 4 + (lane >> 4)] =
      accA1[0] + accA1[1] + accA1[2] + accA1[3];
  __syncthreads();
  if (tid < 32) {
    float s = 0.f;
#pragma unroll
    for (int q = 0; q < 16; ++q) s += asum_s[tid][q];
    actsum_part[blk * HID + tid] = s;
  }

  // ---------------- phase B: corr1T + xsum, plain bf16 MFMA ----------------
  const int itA = (2 * wv) * 16;      // wave's i-tile bases within chunk
  const int itB = (2 * wv + 1) * 16;

  for (int t = 0; t < 16; ++t) {
    const int k0 = t * 128;
    __syncthreads();
    {  // stage x^T bf16: pack (b, b+1) pairs -> one b32 write per i
      const float* xr0 = x + (size_t)(b0 + 2 * rp) * IND + k0 + kg;
      const float* xr1 = xr0 + IND;
#pragma unroll
      for (int d4 = 0; d4 < 4; ++d4) {
        float4 v0 = *(const float4*)(xr0 + 4 * d4);
        float4 v1 = *(const float4*)(xr1 + 4 * d4);
        const int cb = kg + 4 * d4;   // i within chunk
        ushort2 p;
        p.x = f2bf(v0.x); p.y = f2bf(v1.x);
        *(ushort2*)(&xsT[(cb + 0) * SB + 2 * rp]) = p;
        p.x = f2bf(v0.y); p.y = f2bf(v1.y);
        *(ushort2*)(&xsT[(cb + 1) * SB + 2 * rp]) = p;
        p.x = f2bf(v0.z); p.y = f2bf(v1.z);
        *(ushort2*)(&xsT[(cb + 2) * SB + 2 * rp]) = p;
        p.x = f2bf(v0.w); p.y = f2bf(v1.w);
        *(ushort2*)(&xsT[(cb + 3) * SB + 2 * rp]) = p;
      }
    }
    __syncthreads();

    f32x4 c00 = {0.f,0.f,0.f,0.f}, c01 = {0.f,0.f,0.f,0.f}, c02 = {0.f,0.f,0.f,0.f};
    f32x4 c10 = {0.f,0.f,0.f,0.f}, c11 = {0.f,0.f,0.f,0.f}, c12 = {0.f,0.f,0.f,0.f};
#pragma unroll
    for (int bs = 0; bs < 2; ++bs) {
      const int bb = bs * 32 + ksub;
      bf16x8 a0 = *(const bf16x8*)(&xsT[(itA + arow) * SB + bb]);
      bf16x8 a1 = *(const bf16x8*)(&xsT[(itB + arow) * SB + bb]);
      bf16x8 e0 = *(const bf16x8*)(&asT[arow * SB + bb]);          // j 0..15
      bf16x8 e1 = *(const bf16x8*)(&asT[(16 + arow) * SB + bb]);   // j 16..31
      bf16x8 e2 = *(const bf16x8*)(&asT[(32 + arow) * SB + bb]);   // ones col
      c00 = __builtin_amdgcn_mfma_f32_16x16x32_bf16(a0, e0, c00, 0, 0, 0);
      c01 = __builtin_amdgcn_mfma_f32_16x16x32_bf16(a0, e1, c01, 0, 0, 0);
      c02 = __builtin_amdgcn_mfma_f32_16x16x32_bf16(a0, e2, c02, 0, 0, 0);
      c10 = __builtin_amdgcn_mfma_f32_16x16x32_bf16(a1, e0, c10, 0, 0, 0);
      c11 = __builtin_amdgcn_mfma_f32_16x16x32_bf16(a1, e1, c11, 0, 0, 0);
      c12 = __builtin_amdgcn_mfma_f32_16x16x32_bf16(a1, e2, c12, 0, 0, 0);
    }
    // C: col(j) = arow, rows(i) = (lane>>4)*4 + r -> 4 contig i = float4 store
    float* basep = corr1T_part + (size_t)blk * (IND * HID);
    const int giA = k0 + itA + ((lane >> 4) << 2);
    const int giB = k0 + itB + ((lane >> 4) << 2);
    *(f32x4*)(basep + (size_t)arow * IND + giA) = c00;
    *(f32x4*)(basep + (size_t)(16 + arow) * IND + giA) = c01;
    *(f32x4*)(basep + (size_t)arow * IND + giB) = c10;
    *(f32x4*)(basep + (size_t)(16 + arow) * IND + giB) = c11;
    if (arow == 0) {  // j=32 column = xsum
      *(f32x4*)(xsum_part + (size_t)blk * IND + giA) = c02;
      *(f32x4*)(xsum_part + (size_t)blk * IND + giB) = c12;
    }
  }
}

// ---------------------------------------------------------------------------
// K1b: deterministic reduce of corr1T/xsum/actsum partials (256 slices).
// ---------------------------------------------------------------------------
__global__ __launch_bounds__(256) void k_red1(
    const float* __restrict__ c1p, const float* __restrict__ xsp,
    const float* __restrict__ asp,
    float* __restrict__ corr1T, float* __restrict__ xsum,
    float* __restrict__ actsum) {
  const int e = blockIdx.x * 256 + threadIdx.x;  // < 65536
  float s = 0.f;
#pragma unroll 8
  for (int c = 0; c < NSL; ++c) s += c1p[(size_t)c * (IND * HID) + e];
  corr1T[e] = s;
  if (e < IND) {
    float t = 0.f;
#pragma unroll 8
    for (int c = 0; c < NSL; ++c) t += xsp[(size_t)c * IND + e];
    xsum[e] = t;
  }
  if (e < HID) {
    float t = 0.f;
#pragma unroll 8
    for (int c = 0; c < NSL; ++c) t += asp[(size_t)c * HID + e];
    actsum[e] = t;
  }
}

// ---------------------------------------------------------------------------
// K3: forward layer 2 + privatized corr2/outsum partials (fp32, r9-proven).
// ---------------------------------------------------------------------------
__global__ __launch_bounds__(256, 2) void k_fwd2p(
    const float* __restrict__ act, const float* __restrict__ w2,
    float* __restrict__ out, float* __restrict__ corr2_part,
    float* __restrict__ outsum_part) {
  const int tid = threadIdx.x;
  const int o = (blockIdx.x & 1) * 256 + tid;
  const int chunk = blockIdx.x >> 1;
  const int b0 = chunk * 128;

  __shared__ float act_s[128][HID];
  {
    const float4* ag = (const float4*)(act + (size_t)b0 * HID);
    float4* as = (float4*)(&act_s[0][0]);
#pragma unroll
    for (int q = 0; q < 4; ++q) as[tid + 256 * q] = ag[tid + 256 * q];
  }

  const float4* w2p = (const float4*)(w2 + (size_t)o * HID);
  float4 w0 = w2p[0], w1r = w2p[1], w2r_ = w2p[2], w3 = w2p[3];
  float4 w4 = w2p[4], w5 = w2p[5], w6 = w2p[6], w7 = w2p[7];

  float4 s0{0,0,0,0}, s1{0,0,0,0}, s2{0,0,0,0}, s3{0,0,0,0};
  float4 s4{0,0,0,0}, s5{0,0,0,0}, s6{0,0,0,0}, s7{0,0,0,0};
  float osum = 0.f;

  __syncthreads();
  for (int b = 0; b < 128; ++b) {
    const float4* ar = (const float4*)(&act_s[b][0]);
    float4 a0 = ar[0], a1 = ar[1], a2 = ar[2], a3 = ar[3];
    float4 a4 = ar[4], a5 = ar[5], a6 = ar[6], a7 = ar[7];
    float z = 0.f;
    DOT4(z, a0, w0); DOT4(z, a1, w1r); DOT4(z, a2, w2r_); DOT4(z, a3, w3);
    DOT4(z, a4, w4); DOT4(z, a5, w5);  DOT4(z, a6, w6);   DOT4(z, a7, w7);
    float ov = 1.0f / (1.0f + __expf(-z)) - 0.4f;
    out[(size_t)(b0 + b) * OUTD + o] = ov;
    osum += ov;
    UPD4(s0, a0, ov); UPD4(s1, a1, ov); UPD4(s2, a2, ov); UPD4(s3, a3, ov);
    UPD4(s4, a4, ov); UPD4(s5, a5, ov); UPD4(s6, a6, ov); UPD4(s7, a7, ov);
  }

  float* c = corr2_part + (size_t)chunk * (HID * OUTD) + o;
  c[0 * OUTD]  = s0.x; c[1 * OUTD]  = s0.y; c[2 * OUTD]  = s0.z; c[3 * OUTD]  = s0.w;
  c[4 * OUTD]  = s1.x; c[5 * OUTD]  = s1.y; c[6 * OUTD]  = s1.z; c[7 * OUTD]  = s1.w;
  c[8 * OUTD]  = s2.x; c[9 * OUTD]  = s2.y; c[10 * OUTD] = s2.z; c[11 * OUTD] = s2.w;
  c[12 * OUTD] = s3.x; c[13 * OUTD] = s3.y; c[14 * OUTD] = s3.z; c[15 * OUTD] = s3.w;
  c[16 * OUTD] = s4.x; c[17 * OUTD] = s4.y; c[18 * OUTD] = s4.z; c[19 * OUTD] = s4.w;
  c[20 * OUTD] = s5.x; c[21 * OUTD] = s5.y; c[22 * OUTD] = s5.z; c[23 * OUTD] = s5.w;
  c[24 * OUTD] = s6.x; c[25 * OUTD] = s6.y; c[26 * OUTD] = s6.z; c[27 * OUTD] = s6.w;
  c[28 * OUTD] = s7.x; c[29 * OUTD] = s7.y; c[30 * OUTD] = s7.z; c[31 * OUTD] = s7.w;
  outsum_part[(size_t)chunk * OUTD + o] = osum;
}

// ---------------------------------------------------------------------------
// K3b: deterministic reduce of corr2/outsum partials (128 slices).
// ---------------------------------------------------------------------------
__global__ __launch_bounds__(256) void k_red2(
    const float* __restrict__ corr2_part, const float* __restrict__ outsum_part,
    float* __restrict__ corr2, float* __restrict__ outsum) {
  const int e = blockIdx.x * 256 + threadIdx.x;  // < 16384
  float s = 0.f;
#pragma unroll 8
  for (int c = 0; c < C2; ++c) s += corr2_part[(size_t)c * (HID * OUTD) + e];
  corr2[e] = s;
  if (e < OUTD) {
    float t = 0.f;
#pragma unroll 8
    for (int c = 0; c < C2; ++c) t += outsum_part[(size_t)c * OUTD + e];
    outsum[e] = t;
  }
}

// ---------------------------------------------------------------------------
// K4: w1_new[h,i] = (w1[h,i] + dw1T[i,h]) / ||row h||_2 ; corr1T[h][i].
// ---------------------------------------------------------------------------
__global__ __launch_bounds__(256) void k_w1(
    const float* __restrict__ w1, const float* __restrict__ heb,
    const float* __restrict__ corr1T, const float* __restrict__ xsum,
    const float* __restrict__ actsum, float* __restrict__ w1out) {
  const int h = blockIdx.x;
  const int tid = threadIdx.x;
  const float ash = actsum[h];
  const float4* heb4 = (const float4*)heb;

  float val[8];
  float ss = 0.f;
#pragma unroll
  for (int r = 0; r < 8; ++r) {
    const int i = tid + 256 * r;
    float4 c = heb4[(size_t)i * HID + h];
    float v = w1[(size_t)h * IND + i] + 16384.0f * c.w +
              c.x * corr1T[(size_t)h * IND + i] + c.y * xsum[i] + c.z * ash;
    val[r] = v;
    ss += v * v;
  }

  __shared__ float red[256];
  red[tid] = ss;
  __syncthreads();
  for (int s = 128; s > 0; s >>= 1) {
    if (tid < s) red[tid] += red[tid + s];
    __syncthreads();
  }
  const float inv = 1.0f / sqrtf(red[0]);
#pragma unroll
  for (int r = 0; r < 8; ++r) {
    const int i = tid + 256 * r;
    w1out[(size_t)h * IND + i] = val[r] * inv;
  }
}

// ---------------------------------------------------------------------------
// K5: w2_new[o,h] = (w2[o,h] + dw2T[h,o]) / ||row o||_2
// ---------------------------------------------------------------------------
__global__ __launch_bounds__(256) void k_w2(
    const float* __restrict__ w2, const float* __restrict__ heb,
    const float* __restrict__ corr2, const float* __restrict__ actsum,
    const float* __restrict__ outsum, float* __restrict__ w2out) {
  const int o = blockIdx.x * 256 + threadIdx.x;
  const float oso = outsum[o];
  const float4* heb4 = (const float4*)heb;

  float val[HID];
  float ss = 0.f;
#pragma unroll
  for (int h = 0; h < HID; ++h) {
    float4 c = heb4[(size_t)(HID * IND) + (size_t)h * OUTD + o];
    float v = w2[(size_t)o * HID + h] + 16384.0f * c.w +
              c.x * corr2[(size_t)h * OUTD + o] + c.y * actsum[h] + c.z * oso;
    val[h] = v;
    ss += v * v;
  }
  const float inv = 1.0f / sqrtf(ss);
#pragma unroll
  for (int h = 0; h < HID; ++h) w2out[(size_t)o * HID + h] = val[h] * inv;
}

// ---------------------------------------------------------------------------
extern "C" void kernel_launch(void* const* d_in, const int* in_sizes, int n_in,
                              void* d_out, int out_size, void* d_ws,
                              size_t ws_size, hipStream_t stream) {
  const float* x   = (const float*)d_in[0];   // [16384, 2048]
  const float* w1  = (const float*)d_in[1];   // [32, 2048]
  const float* w2  = (const float*)d_in[2];   // [512, 32]
  const float* heb = (const float*)d_in[3];   // [81920, 4]

  float* out = (float*)d_out;                 // [16384, 512]
  float* w1o = out + (size_t)BATCH * OUTD;    // [32, 2048]
  float* w2o = w1o + (size_t)HID * IND;       // [512, 32]

  float* ws = (float*)d_ws;
  float* act         = ws;                                       // 524288
  float* corr1T      = act + (size_t)BATCH * HID;                // 65536 [h][i]
  float* corr2       = corr1T + (size_t)IND * HID;               // 16384
  float* xsum        = corr2 + (size_t)HID * OUTD;               // 2048
  float* actsum      = xsum + IND;                               // 32
  float* outsum      = actsum + HID;                             // 512
  float* corr1T_part = outsum + OUTD;                            // 256*65536
  float* xsum_part   = corr1T_part + (size_t)NSL * IND * HID;    // 256*2048
  float* actsum_part = xsum_part + (size_t)NSL * IND;            // 256*32
  float* corr2_part  = actsum_part + (size_t)NSL * HID;          // 128*16384
  float* outsum_part = corr2_part + (size_t)C2 * HID * OUTD;     // 128*512

  k_l1   <<<256, 256, 0, stream>>>(x, w1, act, corr1T_part, xsum_part,
                                   actsum_part);
  k_red1 <<<256, 256, 0, stream>>>(corr1T_part, xsum_part, actsum_part,
                                   corr1T, xsum, actsum);
  k_fwd2p<<<256, 256, 0, stream>>>(act, w2, out, corr2_part, outsum_part);
  k_red2 <<<64, 256, 0, stream>>>(corr2_part, outsum_part, corr2, outsum);
  k_w1   <<<32, 256, 0, stream>>>(w1, heb, corr1T, xsum, actsum, w1o);
  k_w2   <<<2, 256, 0, stream>>>(w2, heb, corr2, actsum, outsum, w2o);
}

// Round 14
// 162.019 us; speedup vs baseline: 1.5856x; 1.0344x over previous
//
#include <hip/hip_runtime.h>
#include <math.h>

// Problem constants
constexpr int BATCH = 16384;
constexpr int IND   = 2048;   // INPUT
constexpr int HID   = 32;     // HIDDEN
constexpr int OUTD  = 512;    // OUTPUT

constexpr int NSL = 256;      // k_l1 blocks = corr1/xsum/actsum partial slices
constexpr int NC2 = 256;      // corr2 b-chunks (64 b each)

constexpr int SA = 136;       // bf16 row stride, phase-A tiles (128 k + pad)
constexpr int SB = 72;        // bf16 row stride, phase-B tiles (64 b + pad)

typedef __attribute__((ext_vector_type(8))) short bf16x8;
typedef __attribute__((ext_vector_type(4))) float f32x4;

__device__ __forceinline__ unsigned short f2bf(float f) {
  unsigned u = __float_as_uint(f);
  u += 0x7FFFu + ((u >> 16) & 1u);          // round-to-nearest-even
  return (unsigned short)(u >> 16);
}
__device__ __forceinline__ float bf2f(unsigned short h) {
  return __uint_as_float(((unsigned)h) << 16);
}
__device__ __forceinline__ void split2(float f, unsigned short& hi,
                                       unsigned short& lo) {
  hi = f2bf(f);
  lo = f2bf(f - bf2f(hi));
}

#define UPD4(C, A, S)                 \
  (C).x = fmaf((S), (A).x, (C).x);    \
  (C).y = fmaf((S), (A).y, (C).y);    \
  (C).z = fmaf((S), (A).z, (C).z);    \
  (C).w = fmaf((S), (A).w, (C).w);

#define DOT4(Z, A, W)                 \
  (Z) = fmaf((A).x, (W).x, (Z));      \
  (Z) = fmaf((A).y, (W).y, (Z));      \
  (Z) = fmaf((A).z, (W).z, (Z));      \
  (Z) = fmaf((A).w, (W).w, (Z));

// ---------------------------------------------------------------------------
// K1: FUSED layer-1, MFMA, 512 threads (r13 had 256 thr = 1 wave/SIMD at
// grid 256 -> occupancy 10.6%, everything latency-exposed, 95us).
// 8 waves: phase A wave = (row-tile rt 0..3) x (h-tile ht 0..1); phase B
// wave = i-tile 0..7. Phase-B x^T staging XOR-swizzled (r13's ushort2
// transpose stores were 8-way bank-conflicted: 7.5M conflict cycles).
// Split-bf16 phase A (precision for out), plain bf16 phase B.
// grid = 256 x 512; block owns b-rows [blk*64, +64).
// ---------------------------------------------------------------------------
__global__ __launch_bounds__(512) void k_l1(
    const float* __restrict__ x, const float* __restrict__ w1,
    float* __restrict__ act, float* __restrict__ corr1T_part,
    float* __restrict__ xsum_part, float* __restrict__ actsum_part) {
  const int tid = threadIdx.x;
  const int blk = blockIdx.x;
  const int b0 = blk * 64;
  const int lane = tid & 63;
  const int wv = tid >> 6;                 // 0..7
  const int arow = lane & 15;
  const int m4 = lane >> 4;                // 0..3
  const int ksub = m4 * 8;
  const int rt = wv & 3;                   // phase-A row-tile
  const int ht = wv >> 2;                  // phase-A h-tile

  __shared__ unsigned short xh_s[64 * SA];
  __shared__ unsigned short xl_s[64 * SA];
  __shared__ unsigned short wh_s[32 * SA];
  __shared__ unsigned short wl_s[32 * SA];
  __shared__ unsigned short xsT[128 * SB];   // x^T bf16 [i][b], XOR-swizzled
  __shared__ unsigned short asT[48 * SB];    // act^T bf16 [h][b]; rows 32..47 ones/zeros
  __shared__ float asum_s[32][16];

  for (int e = tid; e < 16 * SB; e += 512)
    asT[32 * SB + e] = (e < 64) ? (unsigned short)0x3F80 : (unsigned short)0;

  // ---------------- phase A: act = relu(x @ w1T), split bf16 ----------------
  f32x4 accA = {0.f, 0.f, 0.f, 0.f};

  const int rp = tid >> 4;                 // 0..31 (row-pair / w-row)
  const int kg = (tid & 15) * 8;           // k-offset within chunk

  for (int kc = 0; kc < 16; ++kc) {
    const int k0 = kc * 128;
    __syncthreads();
    {  // stage x hi/lo: 2 rows x 8 k per thread
      const float* xr0 = x + (size_t)(b0 + 2 * rp) * IND + k0 + kg;
      const float* xr1 = xr0 + IND;
#pragma unroll
      for (int d4 = 0; d4 < 2; ++d4) {
        float4 v0 = *(const float4*)(xr0 + 4 * d4);
        float4 v1 = *(const float4*)(xr1 + 4 * d4);
        ushort4 h0, l0, h1, l1;
        split2(v0.x, h0.x, l0.x); split2(v0.y, h0.y, l0.y);
        split2(v0.z, h0.z, l0.z); split2(v0.w, h0.w, l0.w);
        split2(v1.x, h1.x, l1.x); split2(v1.y, h1.y, l1.y);
        split2(v1.z, h1.z, l1.z); split2(v1.w, h1.w, l1.w);
        const int cb = kg + 4 * d4;
        *(ushort4*)(&xh_s[(2 * rp) * SA + cb]) = h0;
        *(ushort4*)(&xh_s[(2 * rp + 1) * SA + cb]) = h1;
        *(ushort4*)(&xl_s[(2 * rp) * SA + cb]) = l0;
        *(ushort4*)(&xl_s[(2 * rp + 1) * SA + cb]) = l1;
      }
    }
    {  // stage w1 hi/lo: row rp, 8 k per thread
      const float* wr_ = w1 + (size_t)rp * IND + k0 + kg;
#pragma unroll
      for (int d4 = 0; d4 < 2; ++d4) {
        float4 v = *(const float4*)(wr_ + 4 * d4);
        ushort4 hh, ll;
        split2(v.x, hh.x, ll.x); split2(v.y, hh.y, ll.y);
        split2(v.z, hh.z, ll.z); split2(v.w, hh.w, ll.w);
        const int cb = kg + 4 * d4;
        *(ushort4*)(&wh_s[rp * SA + cb]) = hh;
        *(ushort4*)(&wl_s[rp * SA + cb]) = ll;
      }
    }
    __syncthreads();

#pragma unroll
    for (int ks = 0; ks < 4; ++ks) {
      const int kk = ks * 32 + ksub;
      bf16x8 ah = *(const bf16x8*)(&xh_s[(rt * 16 + arow) * SA + kk]);
      bf16x8 al = *(const bf16x8*)(&xl_s[(rt * 16 + arow) * SA + kk]);
      bf16x8 bh = *(const bf16x8*)(&wh_s[(ht * 16 + arow) * SA + kk]);
      bf16x8 bl_ = *(const bf16x8*)(&wl_s[(ht * 16 + arow) * SA + kk]);
      accA = __builtin_amdgcn_mfma_f32_16x16x32_bf16(ah, bh, accA, 0, 0, 0);
      accA = __builtin_amdgcn_mfma_f32_16x16x32_bf16(ah, bl_, accA, 0, 0, 0);
      accA = __builtin_amdgcn_mfma_f32_16x16x32_bf16(al, bh, accA, 0, 0, 0);
    }
  }

#pragma unroll
  for (int r = 0; r < 4; ++r) accA[r] = fmaxf(accA[r], 0.f);

  // C layout: col = lane&15 (h within tile), row = m4*4 + r (b within tile)
  const int bl = rt * 16 + (m4 << 2);
  const int h = ht * 16 + arow;
#pragma unroll
  for (int r = 0; r < 4; ++r)
    act[(size_t)(b0 + bl + r) * HID + h] = accA[r];
  {
    ushort4 pa;
    pa.x = f2bf(accA[0]); pa.y = f2bf(accA[1]);
    pa.z = f2bf(accA[2]); pa.w = f2bf(accA[3]);
    *(ushort4*)(&asT[h * SB + bl]) = pa;
  }
  asum_s[h][rt * 4 + m4] = accA[0] + accA[1] + accA[2] + accA[3];
  __syncthreads();
  if (tid < 32) {
    float s = 0.f;
#pragma unroll
    for (int q = 0; q < 16; ++q) s += asum_s[tid][q];
    actsum_part[blk * HID + tid] = s;
  }

  // ---------------- phase B: corr1T + xsum, plain bf16 MFMA ----------------
  const int ig = tid & 15;                 // i-group (8 i each)
  const int bp = tid >> 4;                 // 0..31 (rows 2bp, 2bp+1)
  const int it = wv * 16;                  // wave's i-tile base
  const int swzr = (((it >> 3) + (arow >> 3)) & 7) * 8;  // = ((i>>3)&7)*8

  for (int t = 0; t < 16; ++t) {
    const int k0 = t * 128;
    __syncthreads();
    {  // stage x^T bf16, XOR-swizzled b-offset: phys_b = b ^ ((i>>3)&7)*8
      const float* xr0 = x + (size_t)(b0 + 2 * bp) * IND + k0 + ig * 8;
      const float* xr1 = xr0 + IND;
      float4 v0a = *(const float4*)(xr0);
      float4 v0b = *(const float4*)(xr0 + 4);
      float4 v1a = *(const float4*)(xr1);
      float4 v1b = *(const float4*)(xr1 + 4);
      const int qb = (2 * bp) ^ ((ig & 7) * 8);
      unsigned short* basew = &xsT[(size_t)(ig * 8) * SB + qb];
      ushort2 p;
      p.x = f2bf(v0a.x); p.y = f2bf(v1a.x); *(ushort2*)(basew + 0 * SB) = p;
      p.x = f2bf(v0a.y); p.y = f2bf(v1a.y); *(ushort2*)(basew + 1 * SB) = p;
      p.x = f2bf(v0a.z); p.y = f2bf(v1a.z); *(ushort2*)(basew + 2 * SB) = p;
      p.x = f2bf(v0a.w); p.y = f2bf(v1a.w); *(ushort2*)(basew + 3 * SB) = p;
      p.x = f2bf(v0b.x); p.y = f2bf(v1b.x); *(ushort2*)(basew + 4 * SB) = p;
      p.x = f2bf(v0b.y); p.y = f2bf(v1b.y); *(ushort2*)(basew + 5 * SB) = p;
      p.x = f2bf(v0b.z); p.y = f2bf(v1b.z); *(ushort2*)(basew + 6 * SB) = p;
      p.x = f2bf(v0b.w); p.y = f2bf(v1b.w); *(ushort2*)(basew + 7 * SB) = p;
    }
    __syncthreads();

    f32x4 c00 = {0.f,0.f,0.f,0.f}, c01 = {0.f,0.f,0.f,0.f}, c02 = {0.f,0.f,0.f,0.f};
#pragma unroll
    for (int bs = 0; bs < 2; ++bs) {
      const int bb = bs * 32 + ksub;
      bf16x8 a0 = *(const bf16x8*)(&xsT[(it + arow) * SB + (bb ^ swzr)]);
      bf16x8 e0 = *(const bf16x8*)(&asT[arow * SB + bb]);          // j 0..15
      bf16x8 e1 = *(const bf16x8*)(&asT[(16 + arow) * SB + bb]);   // j 16..31
      bf16x8 e2 = *(const bf16x8*)(&asT[(32 + arow) * SB + bb]);   // ones
      c00 = __builtin_amdgcn_mfma_f32_16x16x32_bf16(a0, e0, c00, 0, 0, 0);
      c01 = __builtin_amdgcn_mfma_f32_16x16x32_bf16(a0, e1, c01, 0, 0, 0);
      c02 = __builtin_amdgcn_mfma_f32_16x16x32_bf16(a0, e2, c02, 0, 0, 0);
    }
    float* basep = corr1T_part + (size_t)blk * (IND * HID);
    const int gi = k0 + it + (m4 << 2);
    *(f32x4*)(basep + (size_t)arow * IND + gi) = c00;
    *(f32x4*)(basep + (size_t)(16 + arow) * IND + gi) = c01;
    if (arow == 0)
      *(f32x4*)(xsum_part + (size_t)blk * IND + gi) = c02;
  }
}

// ---------------------------------------------------------------------------
// K1b: deterministic reduce of corr1T/xsum/actsum partials (256 slices).
// ---------------------------------------------------------------------------
__global__ __launch_bounds__(256) void k_red1(
    const float* __restrict__ c1p, const float* __restrict__ xsp,
    const float* __restrict__ asp,
    float* __restrict__ corr1T, float* __restrict__ xsum,
    float* __restrict__ actsum) {
  const int e = blockIdx.x * 256 + threadIdx.x;  // < 65536
  float s = 0.f;
#pragma unroll 8
  for (int c = 0; c < NSL; ++c) s += c1p[(size_t)c * (IND * HID) + e];
  corr1T[e] = s;
  if (e < IND) {
    float t = 0.f;
#pragma unroll 8
    for (int c = 0; c < NSL; ++c) t += xsp[(size_t)c * IND + e];
    xsum[e] = t;
  }
  if (e < HID) {
    float t = 0.f;
#pragma unroll 8
    for (int c = 0; c < NSL; ++c) t += asp[(size_t)c * HID + e];
    actsum[e] = t;
  }
}

// ---------------------------------------------------------------------------
// K3: forward layer 2 + privatized corr2/outsum partials. 64-b chunks ->
// grid = 2 o-tiles x 256 chunks = 512 blocks (2 blk/CU; r13's 256 was 1).
// ---------------------------------------------------------------------------
__global__ __launch_bounds__(256, 2) void k_fwd2p(
    const float* __restrict__ act, const float* __restrict__ w2,
    float* __restrict__ out, float* __restrict__ corr2_part,
    float* __restrict__ outsum_part) {
  const int tid = threadIdx.x;
  const int o = (blockIdx.x & 1) * 256 + tid;
  const int chunk = blockIdx.x >> 1;
  const int b0 = chunk * 64;

  __shared__ float act_s[64][HID];
  {
    const float4* ag = (const float4*)(act + (size_t)b0 * HID);
    float4* as = (float4*)(&act_s[0][0]);
#pragma unroll
    for (int q = 0; q < 2; ++q) as[tid + 256 * q] = ag[tid + 256 * q];
  }

  const float4* w2p = (const float4*)(w2 + (size_t)o * HID);
  float4 w0 = w2p[0], w1r = w2p[1], w2r_ = w2p[2], w3 = w2p[3];
  float4 w4 = w2p[4], w5 = w2p[5], w6 = w2p[6], w7 = w2p[7];

  float4 s0{0,0,0,0}, s1{0,0,0,0}, s2{0,0,0,0}, s3{0,0,0,0};
  float4 s4{0,0,0,0}, s5{0,0,0,0}, s6{0,0,0,0}, s7{0,0,0,0};
  float osum = 0.f;

  __syncthreads();
  for (int b = 0; b < 64; ++b) {
    const float4* ar = (const float4*)(&act_s[b][0]);
    float4 a0 = ar[0], a1 = ar[1], a2 = ar[2], a3 = ar[3];
    float4 a4 = ar[4], a5 = ar[5], a6 = ar[6], a7 = ar[7];
    float z = 0.f;
    DOT4(z, a0, w0); DOT4(z, a1, w1r); DOT4(z, a2, w2r_); DOT4(z, a3, w3);
    DOT4(z, a4, w4); DOT4(z, a5, w5);  DOT4(z, a6, w6);   DOT4(z, a7, w7);
    float ov = 1.0f / (1.0f + __expf(-z)) - 0.4f;
    out[(size_t)(b0 + b) * OUTD + o] = ov;
    osum += ov;
    UPD4(s0, a0, ov); UPD4(s1, a1, ov); UPD4(s2, a2, ov); UPD4(s3, a3, ov);
    UPD4(s4, a4, ov); UPD4(s5, a5, ov); UPD4(s6, a6, ov); UPD4(s7, a7, ov);
  }

  float* c = corr2_part + (size_t)chunk * (HID * OUTD) + o;
  c[0 * OUTD]  = s0.x; c[1 * OUTD]  = s0.y; c[2 * OUTD]  = s0.z; c[3 * OUTD]  = s0.w;
  c[4 * OUTD]  = s1.x; c[5 * OUTD]  = s1.y; c[6 * OUTD]  = s1.z; c[7 * OUTD]  = s1.w;
  c[8 * OUTD]  = s2.x; c[9 * OUTD]  = s2.y; c[10 * OUTD] = s2.z; c[11 * OUTD] = s2.w;
  c[12 * OUTD] = s3.x; c[13 * OUTD] = s3.y; c[14 * OUTD] = s3.z; c[15 * OUTD] = s3.w;
  c[16 * OUTD] = s4.x; c[17 * OUTD] = s4.y; c[18 * OUTD] = s4.z; c[19 * OUTD] = s4.w;
  c[20 * OUTD] = s5.x; c[21 * OUTD] = s5.y; c[22 * OUTD] = s5.z; c[23 * OUTD] = s5.w;
  c[24 * OUTD] = s6.x; c[25 * OUTD] = s6.y; c[26 * OUTD] = s6.z; c[27 * OUTD] = s6.w;
  c[28 * OUTD] = s7.x; c[29 * OUTD] = s7.y; c[30 * OUTD] = s7.z; c[31 * OUTD] = s7.w;
  outsum_part[(size_t)chunk * OUTD + o] = osum;
}

// ---------------------------------------------------------------------------
// K3b: deterministic reduce of corr2/outsum partials (256 slices).
// ---------------------------------------------------------------------------
__global__ __launch_bounds__(256) void k_red2(
    const float* __restrict__ corr2_part, const float* __restrict__ outsum_part,
    float* __restrict__ corr2, float* __restrict__ outsum) {
  const int e = blockIdx.x * 256 + threadIdx.x;  // < 16384
  float s = 0.f;
#pragma unroll 8
  for (int c = 0; c < NC2; ++c) s += corr2_part[(size_t)c * (HID * OUTD) + e];
  corr2[e] = s;
  if (e < OUTD) {
    float t = 0.f;
#pragma unroll 8
    for (int c = 0; c < NC2; ++c) t += outsum_part[(size_t)c * OUTD + e];
    outsum[e] = t;
  }
}

// ---------------------------------------------------------------------------
// K4: w1_new[h,i] = (w1[h,i] + dw1T[i,h]) / ||row h||_2 ; corr1T[h][i].
// ---------------------------------------------------------------------------
__global__ __launch_bounds__(256) void k_w1(
    const float* __restrict__ w1, const float* __restrict__ heb,
    const float* __restrict__ corr1T, const float* __restrict__ xsum,
    const float* __restrict__ actsum, float* __restrict__ w1out) {
  const int h = blockIdx.x;
  const int tid = threadIdx.x;
  const float ash = actsum[h];
  const float4* heb4 = (const float4*)heb;

  float val[8];
  float ss = 0.f;
#pragma unroll
  for (int r = 0; r < 8; ++r) {
    const int i = tid + 256 * r;
    float4 c = heb4[(size_t)i * HID + h];
    float v = w1[(size_t)h * IND + i] + 16384.0f * c.w +
              c.x * corr1T[(size_t)h * IND + i] + c.y * xsum[i] + c.z * ash;
    val[r] = v;
    ss += v * v;
  }

  __shared__ float red[256];
  red[tid] = ss;
  __syncthreads();
  for (int s = 128; s > 0; s >>= 1) {
    if (tid < s) red[tid] += red[tid + s];
    __syncthreads();
  }
  const float inv = 1.0f / sqrtf(red[0]);
#pragma unroll
  for (int r = 0; r < 8; ++r) {
    const int i = tid + 256 * r;
    w1out[(size_t)h * IND + i] = val[r] * inv;
  }
}

// ---------------------------------------------------------------------------
// K5: w2_new[o,h] = (w2[o,h] + dw2T[h,o]) / ||row o||_2
// ---------------------------------------------------------------------------
__global__ __launch_bounds__(256) void k_w2(
    const float* __restrict__ w2, const float* __restrict__ heb,
    const float* __restrict__ corr2, const float* __restrict__ actsum,
    const float* __restrict__ outsum, float* __restrict__ w2out) {
  const int o = blockIdx.x * 256 + threadIdx.x;
  const float oso = outsum[o];
  const float4* heb4 = (const float4*)heb;

  float val[HID];
  float ss = 0.f;
#pragma unroll
  for (int h = 0; h < HID; ++h) {
    float4 c = heb4[(size_t)(HID * IND) + (size_t)h * OUTD + o];
    float v = w2[(size_t)o * HID + h] + 16384.0f * c.w +
              c.x * corr2[(size_t)h * OUTD + o] + c.y * actsum[h] + c.z * oso;
    val[h] = v;
    ss += v * v;
  }
  const float inv = 1.0f / sqrtf(ss);
#pragma unroll
  for (int h = 0; h < HID; ++h) w2out[(size_t)o * HID + h] = val[h] * inv;
}

// ---------------------------------------------------------------------------
extern "C" void kernel_launch(void* const* d_in, const int* in_sizes, int n_in,
                              void* d_out, int out_size, void* d_ws,
                              size_t ws_size, hipStream_t stream) {
  const float* x   = (const float*)d_in[0];   // [16384, 2048]
  const float* w1  = (const float*)d_in[1];   // [32, 2048]
  const float* w2  = (const float*)d_in[2];   // [512, 32]
  const float* heb = (const float*)d_in[3];   // [81920, 4]

  float* out = (float*)d_out;                 // [16384, 512]
  float* w1o = out + (size_t)BATCH * OUTD;    // [32, 2048]
  float* w2o = w1o + (size_t)HID * IND;       // [512, 32]

  float* ws = (float*)d_ws;                   // ws ~537 MB; layout ~89 MB
  float* act         = ws;                                       // 524288
  float* corr1T      = act + (size_t)BATCH * HID;                // 65536 [h][i]
  float* corr2       = corr1T + (size_t)IND * HID;               // 16384
  float* xsum        = corr2 + (size_t)HID * OUTD;               // 2048
  float* actsum      = xsum + IND;                               // 32
  float* outsum      = actsum + HID;                             // 512
  float* corr1T_part = outsum + OUTD;                            // 256*65536
  float* xsum_part   = corr1T_part + (size_t)NSL * IND * HID;    // 256*2048
  float* actsum_part = xsum_part + (size_t)NSL * IND;            // 256*32
  float* corr2_part  = actsum_part + (size_t)NSL * HID;          // 256*16384
  float* outsum_part = corr2_part + (size_t)NC2 * HID * OUTD;    // 256*512

  k_l1   <<<256, 512, 0, stream>>>(x, w1, act, corr1T_part, xsum_part,
                                   actsum_part);
  k_red1 <<<256, 256, 0, stream>>>(corr1T_part, xsum_part, actsum_part,
                                   corr1T, xsum, actsum);
  k_fwd2p<<<512, 256, 0, stream>>>(act, w2, out, corr2_part, outsum_part);
  k_red2 <<<64, 256, 0, stream>>>(corr2_part, outsum_part, corr2, outsum);
  k_w1   <<<32, 256, 0, stream>>>(w1, heb, corr1T, xsum, actsum, w1o);
  k_w2   <<<2, 256, 0, stream>>>(w2, heb, corr2, actsum, outsum, w2o);
}

// Round 15
// 158.548 us; speedup vs baseline: 1.6203x; 1.0219x over previous
//
#include <hip/hip_runtime.h>
#include <math.h>

// Problem constants
constexpr int BATCH = 16384;
constexpr int IND   = 2048;   // INPUT
constexpr int HID   = 32;     // HIDDEN
constexpr int OUTD  = 512;    // OUTPUT

constexpr int NSL = 256;      // k_l1 blocks = corr1/xsum/actsum partial slices
constexpr int NC2 = 256;      // corr2 b-chunks (64 b each)

constexpr int SA = 136;       // bf16 row stride, phase-A tiles (128 k + pad)
constexpr int SB = 72;        // bf16 row stride, phase-B tiles (64 b + pad)

typedef __attribute__((ext_vector_type(8))) short bf16x8;
typedef __attribute__((ext_vector_type(4))) float f32x4;

__device__ __forceinline__ unsigned short f2bf(float f) {
  unsigned u = __float_as_uint(f);
  u += 0x7FFFu + ((u >> 16) & 1u);          // round-to-nearest-even
  return (unsigned short)(u >> 16);
}
__device__ __forceinline__ float bf2f(unsigned short h) {
  return __uint_as_float(((unsigned)h) << 16);
}
__device__ __forceinline__ void split2(float f, unsigned short& hi,
                                       unsigned short& lo) {
  hi = f2bf(f);
  lo = f2bf(f - bf2f(hi));
}

#define UPD4(C, A, S)                 \
  (C).x = fmaf((S), (A).x, (C).x);    \
  (C).y = fmaf((S), (A).y, (C).y);    \
  (C).z = fmaf((S), (A).z, (C).z);    \
  (C).w = fmaf((S), (A).w, (C).w);

#define DOT4(Z, A, W)                 \
  (Z) = fmaf((A).x, (W).x, (Z));      \
  (Z) = fmaf((A).y, (W).y, (Z));      \
  (Z) = fmaf((A).z, (W).z, (Z));      \
  (Z) = fmaf((A).w, (W).w, (Z));

// ---------------------------------------------------------------------------
// K1: FUSED layer-1, MFMA, 512 thr, DOUBLE-BUFFERED staging (r14: 84us at
// MfmaUtil 4.3% / VALU 15% / HBM 30% — nothing saturated; 1 blk/CU means
// 64 lockstep barriers fully expose load latency; m99-class dbuf is the
// one case where source pipelining pays: no inter-block TLP exists).
// Per chunk: issue next loads -> MFMA current buf -> convert+ds_write next
// buf -> ONE barrier. Phase A split-bf16 (out needs precision), phase B
// plain bf16, XOR-swizzled x^T staging (r14-verified conflict-free).
// LDS arena 111KB: phase-B xsT dbuf aliases phase-A region.
// grid = 256 x 512; block owns b-rows [blk*64, +64).
// ---------------------------------------------------------------------------
__global__ __launch_bounds__(512) void k_l1(
    const float* __restrict__ x, const float* __restrict__ w1,
    float* __restrict__ act, float* __restrict__ corr1T_part,
    float* __restrict__ xsum_part, float* __restrict__ actsum_part) {
  const int tid = threadIdx.x;
  const int blk = blockIdx.x;
  const int b0 = blk * 64;
  const int lane = tid & 63;
  const int wv = tid >> 6;                 // 0..7
  const int arow = lane & 15;
  const int m4 = lane >> 4;                // 0..3
  const int ksub = m4 * 8;
  const int rt = wv & 3;                   // phase-A row-tile
  const int ht = wv >> 2;                  // phase-A h-tile

  // LDS arena. Phase A: XH0,XH1,XL0,XL1 (64xSA each), WH0,WH1,WL0,WL1
  // (32xSA each) = 104448 B. Phase B: XT0,XT1 (128xSB each = 18432 B)
  // alias the phase-A region. asT (48xSB) + asum at the top: 113408 B.
  __shared__ __align__(16) char smem[113664];
  unsigned short* const XH0 = (unsigned short*)(smem);
  unsigned short* const XH1 = (unsigned short*)(smem + 17408);
  unsigned short* const XL0 = (unsigned short*)(smem + 34816);
  unsigned short* const XL1 = (unsigned short*)(smem + 52224);
  unsigned short* const WH0 = (unsigned short*)(smem + 69632);
  unsigned short* const WH1 = (unsigned short*)(smem + 78336);
  unsigned short* const WL0 = (unsigned short*)(smem + 87040);
  unsigned short* const WL1 = (unsigned short*)(smem + 95744);
  unsigned short* const XT0 = (unsigned short*)(smem);
  unsigned short* const XT1 = (unsigned short*)(smem + 18432);
  unsigned short* const asT = (unsigned short*)(smem + 104448);
  float (*asum_s)[16] = (float(*)[16])(smem + 111360);

  for (int e = tid; e < 16 * SB; e += 512)
    asT[32 * SB + e] = (e < 64) ? (unsigned short)0x3F80 : (unsigned short)0;

  // ---------------- phase A: act = relu(x @ w1T), split bf16 ----------------
  const int rp = tid >> 4;                 // 0..31 (row-pair / w-row)
  const int kg = (tid & 15) * 8;           // k-offset within chunk

  float4 px0a, px0b, px1a, px1b, pw0, pw1; // prefetch registers

#define LOADA(K0)                                                    \
  {                                                                  \
    const float* xr0 = x + (size_t)(b0 + 2 * rp) * IND + (K0) + kg;  \
    const float* xr1 = xr0 + IND;                                    \
    px0a = *(const float4*)(xr0);                                    \
    px0b = *(const float4*)(xr0 + 4);                                \
    px1a = *(const float4*)(xr1);                                    \
    px1b = *(const float4*)(xr1 + 4);                                \
    const float* wr_ = w1 + (size_t)rp * IND + (K0) + kg;            \
    pw0 = *(const float4*)(wr_);                                     \
    pw1 = *(const float4*)(wr_ + 4);                                 \
  }

#define STOREA(XHP, XLP, WHP, WLP)                                   \
  {                                                                  \
    ushort4 h, l;                                                    \
    split2(px0a.x, h.x, l.x); split2(px0a.y, h.y, l.y);              \
    split2(px0a.z, h.z, l.z); split2(px0a.w, h.w, l.w);              \
    *(ushort4*)(&(XHP)[(2 * rp) * SA + kg]) = h;                     \
    *(ushort4*)(&(XLP)[(2 * rp) * SA + kg]) = l;                     \
    split2(px0b.x, h.x, l.x); split2(px0b.y, h.y, l.y);              \
    split2(px0b.z, h.z, l.z); split2(px0b.w, h.w, l.w);              \
    *(ushort4*)(&(XHP)[(2 * rp) * SA + kg + 4]) = h;                 \
    *(ushort4*)(&(XLP)[(2 * rp) * SA + kg + 4]) = l;                 \
    split2(px1a.x, h.x, l.x); split2(px1a.y, h.y, l.y);              \
    split2(px1a.z, h.z, l.z); split2(px1a.w, h.w, l.w);              \
    *(ushort4*)(&(XHP)[(2 * rp + 1) * SA + kg]) = h;                 \
    *(ushort4*)(&(XLP)[(2 * rp + 1) * SA + kg]) = l;                 \
    split2(px1b.x, h.x, l.x); split2(px1b.y, h.y, l.y);              \
    split2(px1b.z, h.z, l.z); split2(px1b.w, h.w, l.w);              \
    *(ushort4*)(&(XHP)[(2 * rp + 1) * SA + kg + 4]) = h;             \
    *(ushort4*)(&(XLP)[(2 * rp + 1) * SA + kg + 4]) = l;             \
    split2(pw0.x, h.x, l.x); split2(pw0.y, h.y, l.y);                \
    split2(pw0.z, h.z, l.z); split2(pw0.w, h.w, l.w);                \
    *(ushort4*)(&(WHP)[rp * SA + kg]) = h;                           \
    *(ushort4*)(&(WLP)[rp * SA + kg]) = l;                           \
    split2(pw1.x, h.x, l.x); split2(pw1.y, h.y, l.y);                \
    split2(pw1.z, h.z, l.z); split2(pw1.w, h.w, l.w);                \
    *(ushort4*)(&(WHP)[rp * SA + kg + 4]) = h;                       \
    *(ushort4*)(&(WLP)[rp * SA + kg + 4]) = l;                       \
  }

  f32x4 accA = {0.f, 0.f, 0.f, 0.f};

  LOADA(0);
  STOREA(XH0, XL0, WH0, WL0);
  __syncthreads();

  for (int kc = 0; kc < 16; ++kc) {
    if (kc < 15) LOADA((kc + 1) * 128);    // issue next chunk's loads EARLY

    const unsigned short* xh = (kc & 1) ? XH1 : XH0;
    const unsigned short* xl = (kc & 1) ? XL1 : XL0;
    const unsigned short* wh = (kc & 1) ? WH1 : WH0;
    const unsigned short* wl = (kc & 1) ? WL1 : WL0;
#pragma unroll
    for (int ks = 0; ks < 4; ++ks) {
      const int kk = ks * 32 + ksub;
      bf16x8 ah = *(const bf16x8*)(&xh[(rt * 16 + arow) * SA + kk]);
      bf16x8 al = *(const bf16x8*)(&xl[(rt * 16 + arow) * SA + kk]);
      bf16x8 bh = *(const bf16x8*)(&wh[(ht * 16 + arow) * SA + kk]);
      bf16x8 bl_ = *(const bf16x8*)(&wl[(ht * 16 + arow) * SA + kk]);
      accA = __builtin_amdgcn_mfma_f32_16x16x32_bf16(ah, bh, accA, 0, 0, 0);
      accA = __builtin_amdgcn_mfma_f32_16x16x32_bf16(ah, bl_, accA, 0, 0, 0);
      accA = __builtin_amdgcn_mfma_f32_16x16x32_bf16(al, bh, accA, 0, 0, 0);
    }

    if (kc < 15) {
      if ((kc + 1) & 1) { STOREA(XH1, XL1, WH1, WL1); }
      else              { STOREA(XH0, XL0, WH0, WL0); }
    }
    __syncthreads();
  }

#pragma unroll
  for (int r = 0; r < 4; ++r) accA[r] = fmaxf(accA[r], 0.f);

  // C layout: col = lane&15 (h within tile), row = m4*4 + r (b within tile)
  const int bl = rt * 16 + (m4 << 2);
  const int h = ht * 16 + arow;
#pragma unroll
  for (int r = 0; r < 4; ++r)
    act[(size_t)(b0 + bl + r) * HID + h] = accA[r];
  {
    ushort4 pa;
    pa.x = f2bf(accA[0]); pa.y = f2bf(accA[1]);
    pa.z = f2bf(accA[2]); pa.w = f2bf(accA[3]);
    *(ushort4*)(&asT[h * SB + bl]) = pa;
  }
  asum_s[h][rt * 4 + m4] = accA[0] + accA[1] + accA[2] + accA[3];
  __syncthreads();                         // asT/asum ready; phase-A bufs dead
  if (tid < 32) {
    float s = 0.f;
#pragma unroll
    for (int q = 0; q < 16; ++q) s += asum_s[tid][q];
    actsum_part[blk * HID + tid] = s;
  }

  // ---------------- phase B: corr1T + xsum, plain bf16 MFMA ----------------
  const int ig = tid & 15;                 // i-group (8 i each)
  const int bp = tid >> 4;                 // 0..31 (rows 2bp, 2bp+1)
  const int it = wv * 16;                  // wave's i-tile base
  const int swzr = (((it >> 3) + (arow >> 3)) & 7) * 8;  // = ((i>>3)&7)*8

#define LOADB(K0)                                                       \
  {                                                                     \
    const float* xr0 = x + (size_t)(b0 + 2 * bp) * IND + (K0) + ig * 8; \
    const float* xr1 = xr0 + IND;                                       \
    px0a = *(const float4*)(xr0);                                       \
    px0b = *(const float4*)(xr0 + 4);                                   \
    px1a = *(const float4*)(xr1);                                       \
    px1b = *(const float4*)(xr1 + 4);                                   \
  }

#define STOREB(XTP)                                                     \
  {                                                                     \
    const int qb = (2 * bp) ^ ((ig & 7) * 8);                           \
    unsigned short* basew = &(XTP)[(size_t)(ig * 8) * SB + qb];         \
    ushort2 p;                                                          \
    p.x = f2bf(px0a.x); p.y = f2bf(px1a.x); *(ushort2*)(basew + 0 * SB) = p; \
    p.x = f2bf(px0a.y); p.y = f2bf(px1a.y); *(ushort2*)(basew + 1 * SB) = p; \
    p.x = f2bf(px0a.z); p.y = f2bf(px1a.z); *(ushort2*)(basew + 2 * SB) = p; \
    p.x = f2bf(px0a.w); p.y = f2bf(px1a.w); *(ushort2*)(basew + 3 * SB) = p; \
    p.x = f2bf(px0b.x); p.y = f2bf(px1b.x); *(ushort2*)(basew + 4 * SB) = p; \
    p.x = f2bf(px0b.y); p.y = f2bf(px1b.y); *(ushort2*)(basew + 5 * SB) = p; \
    p.x = f2bf(px0b.z); p.y = f2bf(px1b.z); *(ushort2*)(basew + 6 * SB) = p; \
    p.x = f2bf(px0b.w); p.y = f2bf(px1b.w); *(ushort2*)(basew + 7 * SB) = p; \
  }

  LOADB(0);
  STOREB(XT0);
  __syncthreads();

  for (int t = 0; t < 16; ++t) {
    if (t < 15) LOADB((t + 1) * 128);      // issue next chunk's loads EARLY

    const unsigned short* xt = (t & 1) ? XT1 : XT0;
    f32x4 c00 = {0.f,0.f,0.f,0.f}, c01 = {0.f,0.f,0.f,0.f}, c02 = {0.f,0.f,0.f,0.f};
#pragma unroll
    for (int bs = 0; bs < 2; ++bs) {
      const int bb = bs * 32 + ksub;
      bf16x8 a0 = *(const bf16x8*)(&xt[(it + arow) * SB + (bb ^ swzr)]);
      bf16x8 e0 = *(const bf16x8*)(&asT[arow * SB + bb]);          // j 0..15
      bf16x8 e1 = *(const bf16x8*)(&asT[(16 + arow) * SB + bb]);   // j 16..31
      bf16x8 e2 = *(const bf16x8*)(&asT[(32 + arow) * SB + bb]);   // ones
      c00 = __builtin_amdgcn_mfma_f32_16x16x32_bf16(a0, e0, c00, 0, 0, 0);
      c01 = __builtin_amdgcn_mfma_f32_16x16x32_bf16(a0, e1, c01, 0, 0, 0);
      c02 = __builtin_amdgcn_mfma_f32_16x16x32_bf16(a0, e2, c02, 0, 0, 0);
    }
    float* basep = corr1T_part + (size_t)blk * (IND * HID);
    const int gi = t * 128 + it + (m4 << 2);
    *(f32x4*)(basep + (size_t)arow * IND + gi) = c00;
    *(f32x4*)(basep + (size_t)(16 + arow) * IND + gi) = c01;
    if (arow == 0)
      *(f32x4*)(xsum_part + (size_t)blk * IND + gi) = c02;

    if (t < 15) {
      if ((t + 1) & 1) { STOREB(XT1); }
      else             { STOREB(XT0); }
    }
    __syncthreads();
  }
}

// ---------------------------------------------------------------------------
// K1b: deterministic reduce of corr1T/xsum/actsum partials (256 slices).
// ---------------------------------------------------------------------------
__global__ __launch_bounds__(256) void k_red1(
    const float* __restrict__ c1p, const float* __restrict__ xsp,
    const float* __restrict__ asp,
    float* __restrict__ corr1T, float* __restrict__ xsum,
    float* __restrict__ actsum) {
  const int e = blockIdx.x * 256 + threadIdx.x;  // < 65536
  float s = 0.f;
#pragma unroll 8
  for (int c = 0; c < NSL; ++c) s += c1p[(size_t)c * (IND * HID) + e];
  corr1T[e] = s;
  if (e < IND) {
    float t = 0.f;
#pragma unroll 8
    for (int c = 0; c < NSL; ++c) t += xsp[(size_t)c * IND + e];
    xsum[e] = t;
  }
  if (e < HID) {
    float t = 0.f;
#pragma unroll 8
    for (int c = 0; c < NSL; ++c) t += asp[(size_t)c * HID + e];
    actsum[e] = t;
  }
}

// ---------------------------------------------------------------------------
// K3: forward layer 2 + privatized corr2/outsum partials. 64-b chunks ->
// grid = 2 o-tiles x 256 chunks = 512 blocks (2 blk/CU).
// ---------------------------------------------------------------------------
__global__ __launch_bounds__(256, 2) void k_fwd2p(
    const float* __restrict__ act, const float* __restrict__ w2,
    float* __restrict__ out, float* __restrict__ corr2_part,
    float* __restrict__ outsum_part) {
  const int tid = threadIdx.x;
  const int o = (blockIdx.x & 1) * 256 + tid;
  const int chunk = blockIdx.x >> 1;
  const int b0 = chunk * 64;

  __shared__ float act_s[64][HID];
  {
    const float4* ag = (const float4*)(act + (size_t)b0 * HID);
    float4* as = (float4*)(&act_s[0][0]);
#pragma unroll
    for (int q = 0; q < 2; ++q) as[tid + 256 * q] = ag[tid + 256 * q];
  }

  const float4* w2p = (const float4*)(w2 + (size_t)o * HID);
  float4 w0 = w2p[0], w1r = w2p[1], w2r_ = w2p[2], w3 = w2p[3];
  float4 w4 = w2p[4], w5 = w2p[5], w6 = w2p[6], w7 = w2p[7];

  float4 s0{0,0,0,0}, s1{0,0,0,0}, s2{0,0,0,0}, s3{0,0,0,0};
  float4 s4{0,0,0,0}, s5{0,0,0,0}, s6{0,0,0,0}, s7{0,0,0,0};
  float osum = 0.f;

  __syncthreads();
  for (int b = 0; b < 64; ++b) {
    const float4* ar = (const float4*)(&act_s[b][0]);
    float4 a0 = ar[0], a1 = ar[1], a2 = ar[2], a3 = ar[3];
    float4 a4 = ar[4], a5 = ar[5], a6 = ar[6], a7 = ar[7];
    float z = 0.f;
    DOT4(z, a0, w0); DOT4(z, a1, w1r); DOT4(z, a2, w2r_); DOT4(z, a3, w3);
    DOT4(z, a4, w4); DOT4(z, a5, w5);  DOT4(z, a6, w6);   DOT4(z, a7, w7);
    float ov = 1.0f / (1.0f + __expf(-z)) - 0.4f;
    out[(size_t)(b0 + b) * OUTD + o] = ov;
    osum += ov;
    UPD4(s0, a0, ov); UPD4(s1, a1, ov); UPD4(s2, a2, ov); UPD4(s3, a3, ov);
    UPD4(s4, a4, ov); UPD4(s5, a5, ov); UPD4(s6, a6, ov); UPD4(s7, a7, ov);
  }

  float* c = corr2_part + (size_t)chunk * (HID * OUTD) + o;
  c[0 * OUTD]  = s0.x; c[1 * OUTD]  = s0.y; c[2 * OUTD]  = s0.z; c[3 * OUTD]  = s0.w;
  c[4 * OUTD]  = s1.x; c[5 * OUTD]  = s1.y; c[6 * OUTD]  = s1.z; c[7 * OUTD]  = s1.w;
  c[8 * OUTD]  = s2.x; c[9 * OUTD]  = s2.y; c[10 * OUTD] = s2.z; c[11 * OUTD] = s2.w;
  c[12 * OUTD] = s3.x; c[13 * OUTD] = s3.y; c[14 * OUTD] = s3.z; c[15 * OUTD] = s3.w;
  c[16 * OUTD] = s4.x; c[17 * OUTD] = s4.y; c[18 * OUTD] = s4.z; c[19 * OUTD] = s4.w;
  c[20 * OUTD] = s5.x; c[21 * OUTD] = s5.y; c[22 * OUTD] = s5.z; c[23 * OUTD] = s5.w;
  c[24 * OUTD] = s6.x; c[25 * OUTD] = s6.y; c[26 * OUTD] = s6.z; c[27 * OUTD] = s6.w;
  c[28 * OUTD] = s7.x; c[29 * OUTD] = s7.y; c[30 * OUTD] = s7.z; c[31 * OUTD] = s7.w;
  outsum_part[(size_t)chunk * OUTD + o] = osum;
}

// ---------------------------------------------------------------------------
// K3b: deterministic reduce of corr2/outsum partials (256 slices).
// ---------------------------------------------------------------------------
__global__ __launch_bounds__(256) void k_red2(
    const float* __restrict__ corr2_part, const float* __restrict__ outsum_part,
    float* __restrict__ corr2, float* __restrict__ outsum) {
  const int e = blockIdx.x * 256 + threadIdx.x;  // < 16384
  float s = 0.f;
#pragma unroll 8
  for (int c = 0; c < NC2; ++c) s += corr2_part[(size_t)c * (HID * OUTD) + e];
  corr2[e] = s;
  if (e < OUTD) {
    float t = 0.f;
#pragma unroll 8
    for (int c = 0; c < NC2; ++c) t += outsum_part[(size_t)c * OUTD + e];
    outsum[e] = t;
  }
}

// ---------------------------------------------------------------------------
// K4: w1_new[h,i] = (w1[h,i] + dw1T[i,h]) / ||row h||_2 ; corr1T[h][i].
// ---------------------------------------------------------------------------
__global__ __launch_bounds__(256) void k_w1(
    const float* __restrict__ w1, const float* __restrict__ heb,
    const float* __restrict__ corr1T, const float* __restrict__ xsum,
    const float* __restrict__ actsum, float* __restrict__ w1out) {
  const int h = blockIdx.x;
  const int tid = threadIdx.x;
  const float ash = actsum[h];
  const float4* heb4 = (const float4*)heb;

  float val[8];
  float ss = 0.f;
#pragma unroll
  for (int r = 0; r < 8; ++r) {
    const int i = tid + 256 * r;
    float4 c = heb4[(size_t)i * HID + h];
    float v = w1[(size_t)h * IND + i] + 16384.0f * c.w +
              c.x * corr1T[(size_t)h * IND + i] + c.y * xsum[i] + c.z * ash;
    val[r] = v;
    ss += v * v;
  }

  __shared__ float red[256];
  red[tid] = ss;
  __syncthreads();
  for (int s = 128; s > 0; s >>= 1) {
    if (tid < s) red[tid] += red[tid + s];
    __syncthreads();
  }
  const float inv = 1.0f / sqrtf(red[0]);
#pragma unroll
  for (int r = 0; r < 8; ++r) {
    const int i = tid + 256 * r;
    w1out[(size_t)h * IND + i] = val[r] * inv;
  }
}

// ---------------------------------------------------------------------------
// K5: w2_new[o,h] = (w2[o,h] + dw2T[h,o]) / ||row o||_2
// ---------------------------------------------------------------------------
__global__ __launch_bounds__(256) void k_w2(
    const float* __restrict__ w2, const float* __restrict__ heb,
    const float* __restrict__ corr2, const float* __restrict__ actsum,
    const float* __restrict__ outsum, float* __restrict__ w2out) {
  const int o = blockIdx.x * 256 + threadIdx.x;
  const float oso = outsum[o];
  const float4* heb4 = (const float4*)heb;

  float val[HID];
  float ss = 0.f;
#pragma unroll
  for (int h = 0; h < HID; ++h) {
    float4 c = heb4[(size_t)(HID * IND) + (size_t)h * OUTD + o];
    float v = w2[(size_t)o * HID + h] + 16384.0f * c.w +
              c.x * corr2[(size_t)h * OUTD + o] + c.y * actsum[h] + c.z * oso;
    val[h] = v;
    ss += v * v;
  }
  const float inv = 1.0f / sqrtf(ss);
#pragma unroll
  for (int h = 0; h < HID; ++h) w2out[(size_t)o * HID + h] = val[h] * inv;
}

// ---------------------------------------------------------------------------
extern "C" void kernel_launch(void* const* d_in, const int* in_sizes, int n_in,
                              void* d_out, int out_size, void* d_ws,
                              size_t ws_size, hipStream_t stream) {
  const float* x   = (const float*)d_in[0];   // [16384, 2048]
  const float* w1  = (const float*)d_in[1];   // [32, 2048]
  const float* w2  = (const float*)d_in[2];   // [512, 32]
  const float* heb = (const float*)d_in[3];   // [81920, 4]

  float* out = (float*)d_out;                 // [16384, 512]
  float* w1o = out + (size_t)BATCH * OUTD;    // [32, 2048]
  float* w2o = w1o + (size_t)HID * IND;       // [512, 32]

  float* ws = (float*)d_ws;                   // ws ~537 MB; layout ~89 MB
  float* act         = ws;                                       // 524288
  float* corr1T      = act + (size_t)BATCH * HID;                // 65536 [h][i]
  float* corr2       = corr1T + (size_t)IND * HID;               // 16384
  float* xsum        = corr2 + (size_t)HID * OUTD;               // 2048
  float* actsum      = xsum + IND;                               // 32
  float* outsum      = actsum + HID;                             // 512
  float* corr1T_part = outsum + OUTD;                            // 256*65536
  float* xsum_part   = corr1T_part + (size_t)NSL * IND * HID;    // 256*2048
  float* actsum_part = xsum_part + (size_t)NSL * IND;            // 256*32
  float* corr2_part  = actsum_part + (size_t)NSL * HID;          // 256*16384
  float* outsum_part = corr2_part + (size_t)NC2 * HID * OUTD;    // 256*512

  k_l1   <<<256, 512, 0, stream>>>(x, w1, act, corr1T_part, xsum_part,
                                   actsum_part);
  k_red1 <<<256, 256, 0, stream>>>(corr1T_part, xsum_part, actsum_part,
                                   corr1T, xsum, actsum);
  k_fwd2p<<<512, 256, 0, stream>>>(act, w2, out, corr2_part, outsum_part);
  k_red2 <<<64, 256, 0, stream>>>(corr2_part, outsum_part, corr2, outsum);
  k_w1   <<<32, 256, 0, stream>>>(w1, heb, corr1T, xsum, actsum, w1o);
  k_w2   <<<2, 256, 0, stream>>>(w2, heb, corr2, actsum, outsum, w2o);
}